// Round 3
// baseline (2159.020 us; speedup 1.0000x reference)
//
#include <hip/hip_runtime.h>
#include <hip/hip_bf16.h>
#include <math.h>

// ---- problem constants ----
#define DIM_      1024
#define DPROJ_    4240   // D_IN_PROJ
#define DINNER_   2048
#define CONVD_    2176   // D_INNER + 2*D_STATE
#define NH_       16
#define HD_       128
#define DSTATE_   64
#define CHUNKL_   256
#define NCHUNK_   16     // SEQLEN/CHUNK
#define SEQL_     4096
#define BATCH_    2
#define NROWS_    8192   // BATCH*SEQLEN

// ---- bf16 <-> f32 helpers (bit-level, round-to-nearest-even) ----
__device__ __forceinline__ unsigned short f2b(float f) {
  unsigned int u = __float_as_uint(f);
  u += 0x7fffu + ((u >> 16) & 1u);
  return (unsigned short)(u >> 16);
}
__device__ __forceinline__ float b2f(unsigned short s) {
  return __uint_as_float((unsigned int)s << 16);
}
__device__ __forceinline__ float4 b4f(ushort4 v) {
  return make_float4(b2f(v.x), b2f(v.y), b2f(v.z), b2f(v.w));
}
__device__ __forceinline__ ushort4 f4b(float4 v) {
  ushort4 r; r.x = f2b(v.x); r.y = f2b(v.y); r.z = f2b(v.z); r.w = f2b(v.w); return r;
}

// =============== row L2 norm (invn = 1/max(||row||,1e-6)) ===============
__global__ __launch_bounds__(256) void rownorm_kernel(const float* __restrict__ w,
                                                      float* __restrict__ invn, int cols) {
  __shared__ float lds[8];
  size_t r = blockIdx.x;
  const float* row = w + r * (size_t)cols;
  float s = 0.f;
  for (int c = threadIdx.x * 4; c < cols; c += 256 * 4) {
    float4 v = *(const float4*)(row + c);
    s += v.x*v.x + v.y*v.y + v.z*v.z + v.w*v.w;
  }
#pragma unroll
  for (int off = 32; off > 0; off >>= 1) s += __shfl_down(s, off);
  if ((threadIdx.x & 63) == 0) lds[threadIdx.x >> 6] = s;
  __syncthreads();
  if (threadIdx.x == 0) {
    float t = lds[0] + lds[1] + lds[2] + lds[3];
    invn[r] = 1.f / fmaxf(sqrtf(t), 1e-6f);
  }
}

// =============== LayerNorm over last dim (1024) -> bf16 ===============
__global__ __launch_bounds__(256) void layernorm_kernel(const float* __restrict__ u,
      const float* __restrict__ w, const float* __restrict__ b,
      unsigned short* __restrict__ out) {
  __shared__ float lds[16];
  size_t r = blockIdx.x;
  const float* row = u + r * DIM_;
  int d = threadIdx.x * 4;
  float4 v = *(const float4*)(row + d);
  float s = v.x + v.y + v.z + v.w;
  float q = v.x*v.x + v.y*v.y + v.z*v.z + v.w*v.w;
#pragma unroll
  for (int off = 32; off > 0; off >>= 1) { s += __shfl_down(s, off); q += __shfl_down(q, off); }
  int wave = threadIdx.x >> 6;
  if ((threadIdx.x & 63) == 0) { lds[wave] = s; lds[8 + wave] = q; }
  __syncthreads();
  float sa = lds[0]+lds[1]+lds[2]+lds[3];
  float sq = lds[8]+lds[9]+lds[10]+lds[11];
  float mu = sa * (1.f / DIM_);
  float var = sq * (1.f / DIM_) - mu * mu;
  float rstd = rsqrtf(var + 1e-5f);
  float4 wv = *(const float4*)(w + d);
  float4 bv = *(const float4*)(b + d);
  float4 o;
  o.x = (v.x - mu) * rstd * wv.x + bv.x;
  o.y = (v.y - mu) * rstd * wv.y + bv.y;
  o.z = (v.z - mu) * rstd * wv.z + bv.z;
  o.w = (v.w - mu) * rstd * wv.w + bv.w;
  *(ushort4*)(out + r * DIM_ + d) = f4b(o);
}

// =============== f32 SGEMM, A stored bf16: C[m,n] = (sum_k A[m,k]*W[n,k]) * invn[n] * alpha ===============
// 128x128 tile, BK=8, 256 threads, 8x8 per thread.  Grid: (ceil(N/128), M/128)
// EPI 0: in_proj split epilogue (z bf16 | xpre bf16 | dtraw f32) with N-guard
// EPI 1: plain f32 store to outp
template<int N, int K, int EPI>
__global__ __launch_bounds__(256) void sgemm_k(
    const unsigned short* __restrict__ A, const float* __restrict__ W,
    const float* __restrict__ invn, float alpha,
    unsigned short* __restrict__ zb, unsigned short* __restrict__ xpre,
    float* __restrict__ dtraw, float* __restrict__ outp)
{
  __shared__ float As[8][128];
  __shared__ float Ws[8][128];
  const int tid = threadIdx.x;
  const int tx = tid & 15, ty = tid >> 4;
  const size_t m0 = (size_t)blockIdx.y * 128;
  const int n0 = blockIdx.x * 128;
  const int lr = tid >> 1;
  const int lc = (tid & 1) * 4;
  float acc[8][8];
#pragma unroll
  for (int i = 0; i < 8; ++i)
#pragma unroll
    for (int j = 0; j < 8; ++j) acc[i][j] = 0.f;

  const unsigned short* Ald = A + (m0 + lr) * (size_t)K + lc;
  const int wrow = n0 + lr;
  const bool wok = (EPI == 1) || (wrow < N);
  const float* Wld = W + (size_t)(wok ? wrow : 0) * K + lc;

  for (int k0 = 0; k0 < K; k0 += 8) {
    ushort4 a4u = *(const ushort4*)(Ald + k0);
    float4 w4 = wok ? *(const float4*)(Wld + k0) : make_float4(0.f,0.f,0.f,0.f);
    float4 a4 = b4f(a4u);
    __syncthreads();
    As[lc+0][lr] = a4.x; As[lc+1][lr] = a4.y; As[lc+2][lr] = a4.z; As[lc+3][lr] = a4.w;
    Ws[lc+0][lr] = w4.x; Ws[lc+1][lr] = w4.y; Ws[lc+2][lr] = w4.z; Ws[lc+3][lr] = w4.w;
    __syncthreads();
#pragma unroll
    for (int kk = 0; kk < 8; ++kk) {
      float av[8], wv[8];
      *(float4*)(av)     = *(const float4*)&As[kk][ty*8];
      *(float4*)(av + 4) = *(const float4*)&As[kk][ty*8 + 4];
      *(float4*)(wv)     = *(const float4*)&Ws[kk][tx*8];
      *(float4*)(wv + 4) = *(const float4*)&Ws[kk][tx*8 + 4];
#pragma unroll
      for (int i = 0; i < 8; ++i)
#pragma unroll
        for (int j = 0; j < 8; ++j) acc[i][j] += av[i] * wv[j];
    }
  }
#pragma unroll
  for (int i = 0; i < 8; ++i) {
    size_t m = m0 + ty*8 + i;
#pragma unroll
    for (int jq = 0; jq < 2; ++jq) {
      int n = n0 + tx*8 + jq*4;
      if (EPI == 0 && (n + 3) >= N) continue;
      float4 v;
      v.x = acc[i][jq*4+0] * invn[n+0] * alpha;
      v.y = acc[i][jq*4+1] * invn[n+1] * alpha;
      v.z = acc[i][jq*4+2] * invn[n+2] * alpha;
      v.w = acc[i][jq*4+3] * invn[n+3] * alpha;
      if (EPI == 0) {
        if (n < DINNER_)              *(ushort4*)(zb   + m * DINNER_ + n)             = f4b(v);
        else if (n < DINNER_ + CONVD_)*(ushort4*)(xpre + m * CONVD_  + (n - DINNER_)) = f4b(v);
        else                          *(float4*) (dtraw + m * NH_    + (n - DINNER_ - CONVD_)) = v;
      } else {
        *(float4*)(outp + m * (size_t)N + n) = v;
      }
    }
  }
}

// =============== depthwise causal conv(4) + SiLU (bf16 in/out) ===============
__global__ __launch_bounds__(256) void conv_silu_kernel(const unsigned short* __restrict__ xpre,
      const float* __restrict__ cw, const float* __restrict__ cb,
      unsigned short* __restrict__ xbc) {
  int c = blockIdx.x * 256 + threadIdx.x;
  if (c >= CONVD_) return;
  int b = blockIdx.z;
  int l0 = blockIdx.y * 64;
  float w0 = cw[c*4+0], w1 = cw[c*4+1], w2 = cw[c*4+2], w3 = cw[c*4+3];
  float bias = cb[c];
  const unsigned short* src = xpre + (size_t)b * SEQL_ * CONVD_ + c;
  float xm3, xm2, xm1;
  if (l0 == 0) { xm3 = 0.f; xm2 = 0.f; xm1 = 0.f; }
  else {
    xm3 = b2f(src[(size_t)(l0-3) * CONVD_]);
    xm2 = b2f(src[(size_t)(l0-2) * CONVD_]);
    xm1 = b2f(src[(size_t)(l0-1) * CONVD_]);
  }
  unsigned short* dst = xbc + ((size_t)b * SEQL_ + l0) * CONVD_ + c;
  for (int t = 0; t < 64; ++t) {
    float x0 = b2f(src[(size_t)(l0 + t) * CONVD_]);
    float v = w0*xm3 + w1*xm2 + w2*xm1 + w3*x0 + bias;
    float sv = v / (1.f + __expf(-v));
    dst[(size_t)t * CONVD_] = f2b(sv);
    xm3 = xm2; xm2 = xm1; xm1 = x0;
  }
}

// =============== dt = softplus(dt_raw + bias); cum = cumsum(dt*A) per chunk ===============
__global__ __launch_bounds__(256) void dtcum_kernel(const float* __restrict__ dtraw,
      const float* __restrict__ dt_bias, const float* __restrict__ A_log,
      float* __restrict__ dtv, float* __restrict__ cum, float* __restrict__ cdec) {
  __shared__ float lds[4];
  int h = blockIdx.x, c = blockIdx.y, b = blockIdx.z;
  int tid = threadIdx.x;
  size_t row = (size_t)b * SEQL_ + c * CHUNKL_ + tid;
  float raw = dtraw[row * NH_ + h] + dt_bias[h];
  float dt = (raw > 20.f) ? raw : log1pf(expf(raw));
  dtv[row * NH_ + h] = dt;
  float v = dt * (-expf(A_log[h]));
  int lane = tid & 63, wave = tid >> 6;
#pragma unroll
  for (int off = 1; off < 64; off <<= 1) {
    float n = __shfl_up(v, off);
    if (lane >= off) v += n;
  }
  if (lane == 63) lds[wave] = v;
  __syncthreads();
  float pre = 0.f;
  for (int w2 = 0; w2 < wave; ++w2) pre += lds[w2];
  v += pre;
  cum[row * NH_ + h] = v;
  if (tid == 255) cdec[((size_t)b * NCHUNK_ + c) * NH_ + h] = __expf(v);
}

// =============== scores[i,j] = C_i . B_j (shared across heads, ngroups=1) ===============
__global__ __launch_bounds__(256) void scores_kernel(const unsigned short* __restrict__ xbc,
                                                     float* __restrict__ scores) {
  __shared__ float Cs[64][64];
  int it = blockIdx.x;  // i-tile of 64
  int c = blockIdx.y, b = blockIdx.z;
  size_t row0 = (size_t)b * SEQL_ + c * CHUNKL_;
  int j = threadIdx.x;
  float Br[64];
  const unsigned short* bp = xbc + (row0 + j) * CONVD_ + DINNER_;
#pragma unroll
  for (int n4 = 0; n4 < 16; ++n4) {
    float4 v = b4f(*(const ushort4*)(bp + n4*4));
    Br[n4*4+0]=v.x; Br[n4*4+1]=v.y; Br[n4*4+2]=v.z; Br[n4*4+3]=v.w;
  }
  {
    int i = threadIdx.x >> 2, q = threadIdx.x & 3;
    const unsigned short* cp = xbc + (row0 + it*64 + i) * CONVD_ + DINNER_ + DSTATE_;
#pragma unroll
    for (int s2 = 0; s2 < 4; ++s2)
      *(float4*)&Cs[i][(q + s2*4)*4] = b4f(*(const ushort4*)(cp + (q + s2*4)*4));
  }
  __syncthreads();
  float* out = scores + ((size_t)b * NCHUNK_ + c) * (CHUNKL_*CHUNKL_) + (size_t)it*64*CHUNKL_ + j;
  for (int i = 0; i < 64; ++i) {
    float s = 0.f;
#pragma unroll
    for (int n = 0; n < 64; ++n) s += Cs[i][n] * Br[n];
    out[(size_t)i * CHUNKL_] = s;
  }
}

// =============== y_intra: y[i,p] = sum_{j<=i} scores[i,j]*exp(cum_i-cum_j)*dt_j * x[j,p] ===============
__global__ __launch_bounds__(256) void yintra_kernel(const unsigned short* __restrict__ xbc,
      const float* __restrict__ scores, const float* __restrict__ dtv,
      const float* __restrict__ cum, unsigned short* __restrict__ y) {
  __shared__ float xs[64][128];
  __shared__ float cumS[256];
  __shared__ float dtS[256];
  int h = blockIdx.x, c = blockIdx.y, b = blockIdx.z;
  size_t row0 = (size_t)b * SEQL_ + c * CHUNKL_;
  int i = threadIdx.x;
  cumS[i] = cum[(row0 + i) * NH_ + h];
  dtS[i]  = dtv[(row0 + i) * NH_ + h];
  float acc[128];
#pragma unroll
  for (int p = 0; p < 128; ++p) acc[p] = 0.f;
  const float* srow = scores + ((size_t)b * NCHUNK_ + c) * (CHUNKL_*CHUNKL_) + (size_t)i * CHUNKL_;
  int wave = i >> 6;
  __syncthreads();
  float cum_i = cumS[i];
  for (int jt = 0; jt < 4; ++jt) {
    {
      int jj = threadIdx.x >> 2, q = threadIdx.x & 3;
      const unsigned short* xp = xbc + (row0 + jt*64 + jj) * CONVD_ + (size_t)h * HD_;
#pragma unroll
      for (int s2 = 0; s2 < 8; ++s2) {
        int p4 = q + s2*4;
        *(float4*)&xs[jj][p4*4] = b4f(*(const ushort4*)(xp + p4*4));
      }
    }
    __syncthreads();
    if (jt <= wave) {
      for (int jj = 0; jj < 64; ++jj) {
        int j = jt*64 + jj;
        if (j <= i) {
          float att = srow[j] * __expf(cum_i - cumS[j]) * dtS[j];
#pragma unroll
          for (int p4 = 0; p4 < 32; ++p4) {
            float4 xv = *(const float4*)&xs[jj][p4*4];
            acc[p4*4+0] += att * xv.x;
            acc[p4*4+1] += att * xv.y;
            acc[p4*4+2] += att * xv.z;
            acc[p4*4+3] += att * xv.w;
          }
        }
      }
    }
    __syncthreads();
  }
  unsigned short* yrow = y + (row0 + i) * DINNER_ + (size_t)h * HD_;
#pragma unroll
  for (int p4 = 0; p4 < 32; ++p4)
    *(ushort4*)(yrow + p4*4) = f4b(make_float4(acc[p4*4+0], acc[p4*4+1], acc[p4*4+2], acc[p4*4+3]));
}

// =============== per-chunk end states: states[h,p,n] = sum_l B[l,n]*dt_l*exp(cum_end-cum_l)*x[l,p] ===============
__global__ __launch_bounds__(128) void states_kernel(const unsigned short* __restrict__ xbc,
      const float* __restrict__ dtv, const float* __restrict__ cum, float* __restrict__ states) {
  __shared__ float coefS[256];
  __shared__ float Bs[64][64];
  int h = blockIdx.x, c = blockIdx.y, b = blockIdx.z;
  size_t row0 = (size_t)b * SEQL_ + c * CHUNKL_;
  int p = threadIdx.x;
  float cum_last = cum[(row0 + 255) * NH_ + h];
  for (int s = p; s < 256; s += 128)
    coefS[s] = dtv[(row0 + s) * NH_ + h] * __expf(cum_last - cum[(row0 + s) * NH_ + h]);
  float acc[64];
#pragma unroll
  for (int n = 0; n < 64; ++n) acc[n] = 0.f;
  for (int lt = 0; lt < 4; ++lt) {
    __syncthreads();
    {
      int lr = p >> 1, q = (p & 1) * 8;
      const unsigned short* bp = xbc + (row0 + lt*64 + lr) * CONVD_ + DINNER_;
#pragma unroll
      for (int s2 = 0; s2 < 8; ++s2)
        *(float4*)&Bs[lr][(q + s2)*4] = b4f(*(const ushort4*)(bp + (q + s2)*4));
    }
    __syncthreads();
    for (int ll = 0; ll < 64; ++ll) {
      int l = lt*64 + ll;
      float xv = b2f(xbc[(row0 + l) * CONVD_ + (size_t)h * HD_ + p]);
      float wv = coefS[l] * xv;
#pragma unroll
      for (int n4 = 0; n4 < 16; ++n4) {
        float4 bv = *(const float4*)&Bs[ll][n4*4];
        acc[n4*4+0] += wv * bv.x; acc[n4*4+1] += wv * bv.y;
        acc[n4*4+2] += wv * bv.z; acc[n4*4+3] += wv * bv.w;
      }
    }
  }
  float* sp = states + ((((size_t)b * NCHUNK_ + c) * NH_ + h) * HD_ + p) * DSTATE_;
#pragma unroll
  for (int n4 = 0; n4 < 16; ++n4)
    *(float4*)(sp + n4*4) = make_float4(acc[n4*4], acc[n4*4+1], acc[n4*4+2], acc[n4*4+3]);
}

// =============== sequential chunk recurrence: prev[c] = prev[c-1]*cdec[c-1] + states[c-1] ===============
__global__ __launch_bounds__(256) void chunkscan_kernel(const float* __restrict__ states,
      const float* __restrict__ cdec, float* __restrict__ prevst) {
  int h = blockIdx.y, b = blockIdx.z;
  int pn = blockIdx.x * 256 + threadIdx.x;  // 0..8191 = p*64+n
  float carry = 0.f;
  for (int c = 0; c < NCHUNK_; ++c) {
    size_t idx = (((size_t)b * NCHUNK_ + c) * NH_ + h) * (HD_*DSTATE_) + pn;
    prevst[idx] = carry;
    carry = carry * cdec[((size_t)b * NCHUNK_ + c) * NH_ + h] + states[idx];
  }
}

// =============== y += exp(cum_l) * (C_l . prev_state[p,:]) + D*x  (bf16 RMW on y) ===============
__global__ __launch_bounds__(128) void yinter_kernel(const unsigned short* __restrict__ xbc,
      const float* __restrict__ prevst, const float* __restrict__ cum,
      const float* __restrict__ Dv, unsigned short* __restrict__ y) {
  __shared__ float ecS[256];
  __shared__ float Cs[64][64];
  int h = blockIdx.x, c = blockIdx.y, b = blockIdx.z;
  size_t row0 = (size_t)b * SEQL_ + c * CHUNKL_;
  int p = threadIdx.x;
  for (int s = p; s < 256; s += 128) ecS[s] = __expf(cum[(row0 + s) * NH_ + h]);
  float S[64];
  const float* sp = prevst + ((((size_t)b * NCHUNK_ + c) * NH_ + h) * HD_ + p) * DSTATE_;
#pragma unroll
  for (int n4 = 0; n4 < 16; ++n4) {
    float4 v = *(const float4*)(sp + n4*4);
    S[n4*4]=v.x; S[n4*4+1]=v.y; S[n4*4+2]=v.z; S[n4*4+3]=v.w;
  }
  float Dh = Dv[h];
  for (int lt = 0; lt < 4; ++lt) {
    __syncthreads();
    {
      int lr = p >> 1, q = (p & 1) * 8;
      const unsigned short* cp = xbc + (row0 + lt*64 + lr) * CONVD_ + DINNER_ + DSTATE_;
#pragma unroll
      for (int s2 = 0; s2 < 8; ++s2)
        *(float4*)&Cs[lr][(q + s2)*4] = b4f(*(const ushort4*)(cp + (q + s2)*4));
    }
    __syncthreads();
    for (int ll = 0; ll < 64; ++ll) {
      int l = lt*64 + ll;
      float dot = 0.f;
#pragma unroll
      for (int n4 = 0; n4 < 16; ++n4) {
        float4 cv = *(const float4*)&Cs[ll][n4*4];
        dot += cv.x*S[n4*4] + cv.y*S[n4*4+1] + cv.z*S[n4*4+2] + cv.w*S[n4*4+3];
      }
      float xv = b2f(xbc[(row0 + l) * CONVD_ + (size_t)h * HD_ + p]);
      size_t yi = (row0 + l) * DINNER_ + (size_t)h * HD_ + p;
      y[yi] = f2b(b2f(y[yi]) + ecS[l] * dot + Dh * xv);
    }
  }
}

// =============== g = y*silu(z); rmsnorm(g)*rms_w  (bf16 in-place over y) ===============
__global__ __launch_bounds__(256) void gate_rms_kernel(const unsigned short* __restrict__ zb,
      const float* __restrict__ rms_w, unsigned short* __restrict__ y) {
  __shared__ float lds[4];
  size_t r = blockIdx.x;
  const unsigned short* zrow = zb + r * DINNER_;
  unsigned short* yrow = y + r * DINNER_;
  int tid = threadIdx.x;
  float g[8];
  float ss = 0.f;
#pragma unroll
  for (int q = 0; q < 2; ++q) {
    int d = q*1024 + tid*4;
    float4 yv = b4f(*(const ushort4*)(yrow + d));
    float4 zv = b4f(*(const ushort4*)(zrow + d));
    float s0 = zv.x / (1.f + __expf(-zv.x));
    float s1 = zv.y / (1.f + __expf(-zv.y));
    float s2 = zv.z / (1.f + __expf(-zv.z));
    float s3 = zv.w / (1.f + __expf(-zv.w));
    g[q*4+0] = yv.x * s0; g[q*4+1] = yv.y * s1;
    g[q*4+2] = yv.z * s2; g[q*4+3] = yv.w * s3;
    ss += g[q*4+0]*g[q*4+0] + g[q*4+1]*g[q*4+1] + g[q*4+2]*g[q*4+2] + g[q*4+3]*g[q*4+3];
  }
#pragma unroll
  for (int off = 32; off > 0; off >>= 1) ss += __shfl_down(ss, off);
  if ((tid & 63) == 0) lds[tid >> 6] = ss;
  __syncthreads();
  float tot = lds[0] + lds[1] + lds[2] + lds[3];
  float scale = rsqrtf(tot * (1.f / DINNER_) + 1e-5f);
#pragma unroll
  for (int q = 0; q < 2; ++q) {
    int d = q*1024 + tid*4;
    float4 wv = *(const float4*)(rms_w + d);
    *(ushort4*)(yrow + d) = f4b(make_float4(g[q*4+0]*scale*wv.x, g[q*4+1]*scale*wv.y,
                                            g[q*4+2]*scale*wv.z, g[q*4+3]*scale*wv.w));
  }
}

extern "C" void kernel_launch(void* const* d_in, const int* in_sizes, int n_in,
                              void* d_out, int out_size, void* d_ws, size_t ws_size,
                              hipStream_t stream) {
  const float* u       = (const float*)d_in[0];
  const float* in_w    = (const float*)d_in[1];
  const float* conv_w  = (const float*)d_in[2];
  const float* conv_b  = (const float*)d_in[3];
  const float* dt_bias = (const float*)d_in[4];
  const float* A_log   = (const float*)d_in[5];
  const float* Dv      = (const float*)d_in[6];
  const float* xn_w    = (const float*)d_in[7];
  const float* xn_b    = (const float*)d_in[8];
  const float* rms_w   = (const float*)d_in[9];
  const float* out_w   = (const float*)d_in[10];
  float* out = (float*)d_out;

  char* wp = (char*)d_ws;
  auto alloc = [&](size_t bytes) -> void* {
    void* p = (void*)wp; wp += (bytes + 1023) & ~(size_t)1023; return p;
  };
  // ~148 MB total with lifetime aliasing (ws budget safety):
  unsigned short* xpre = (unsigned short*)alloc((size_t)NROWS_ * CONVD_ * 2);  // 35.7MB; y aliases
  unsigned short* y    = xpre;  // y (8192x2048 bf16, 33.6MB) reuses xpre after conv consumes it
  unsigned short* zb   = (unsigned short*)alloc((size_t)NROWS_ * DINNER_ * 2); // 33.6MB
  float* dtraw    = (float*)alloc((size_t)NROWS_ * NH_ * 4);
  unsigned short* xbc  = (unsigned short*)alloc((size_t)NROWS_ * CONVD_ * 2);  // 35.7MB
  float* dtv      = (float*)alloc((size_t)NROWS_ * NH_ * 4);
  float* cum      = (float*)alloc((size_t)NROWS_ * NH_ * 4);
  float* cdec     = (float*)alloc((size_t)BATCH_ * NCHUNK_ * NH_ * 4);
  float* invn_in  = (float*)alloc((size_t)DPROJ_ * 4);
  float* invn_out = (float*)alloc((size_t)DIM_ * 4);
  float* scoresB  = (float*)alloc((size_t)BATCH_ * NCHUNK_ * CHUNKL_ * CHUNKL_ * 4); // 8.4MB
  unsigned short* u_ln = (unsigned short*)alloc((size_t)NROWS_ * DIM_ * 2);    // 16.8MB; states aliases
  float* states   = (float*)u_ln;  // states (16.8MB f32) reuses u_ln after in_proj GEMM
  float* prevst   = (float*)alloc((size_t)BATCH_ * NCHUNK_ * NH_ * HD_ * DSTATE_ * 4); // 16.8MB

  rownorm_kernel<<<DPROJ_, 256, 0, stream>>>(in_w, invn_in, DIM_);
  rownorm_kernel<<<DIM_, 256, 0, stream>>>(out_w, invn_out, DINNER_);
  layernorm_kernel<<<NROWS_, 256, 0, stream>>>(u, xn_w, xn_b, u_ln);
  sgemm_k<DPROJ_, DIM_, 0><<<dim3(34, 64), 256, 0, stream>>>(
      u_ln, in_w, invn_in, 0.03125f, zb, xpre, dtraw, nullptr);
  conv_silu_kernel<<<dim3(9, 64, BATCH_), 256, 0, stream>>>(xpre, conv_w, conv_b, xbc);
  dtcum_kernel<<<dim3(NH_, NCHUNK_, BATCH_), 256, 0, stream>>>(dtraw, dt_bias, A_log, dtv, cum, cdec);
  scores_kernel<<<dim3(4, NCHUNK_, BATCH_), 256, 0, stream>>>(xbc, scoresB);
  yintra_kernel<<<dim3(NH_, NCHUNK_, BATCH_), 256, 0, stream>>>(xbc, scoresB, dtv, cum, y);
  states_kernel<<<dim3(NH_, NCHUNK_, BATCH_), 128, 0, stream>>>(xbc, dtv, cum, states);
  chunkscan_kernel<<<dim3(32, NH_, BATCH_), 256, 0, stream>>>(states, cdec, prevst);
  yinter_kernel<<<dim3(NH_, NCHUNK_, BATCH_), 128, 0, stream>>>(xbc, prevst, cum, Dv, y);
  gate_rms_kernel<<<NROWS_, 256, 0, stream>>>(zb, rms_w, y);
  sgemm_k<DIM_, DINNER_, 1><<<dim3(8, 64), 256, 0, stream>>>(
      y, out_w, invn_out, 1.0f, nullptr, nullptr, nullptr, out);
}

// Round 5
// 1065.945 us; speedup vs baseline: 2.0255x; 2.0255x over previous
//
#include <hip/hip_runtime.h>
#include <hip/hip_bf16.h>
#include <math.h>

// ---- problem constants ----
#define DIM_      1024
#define DPROJ_    4240   // D_IN_PROJ
#define NPAD_     4352   // DPROJ_ padded to 34*128 for MFMA tiles
#define DINNER_   2048
#define CONVD_    2176   // D_INNER + 2*D_STATE
#define NH_       16
#define HD_       128
#define DSTATE_   64
#define CHUNKL_   256
#define NCHUNK_   16     // SEQLEN/CHUNK
#define SEQL_     4096
#define BATCH_    2
#define NROWS_    8192   // BATCH*SEQLEN

typedef short bf16x8 __attribute__((ext_vector_type(8)));
typedef float f32x4  __attribute__((ext_vector_type(4)));

// ---- bf16 <-> f32 helpers (bit-level, round-to-nearest-even) ----
__device__ __forceinline__ unsigned short f2b(float f) {
  unsigned int u = __float_as_uint(f);
  u += 0x7fffu + ((u >> 16) & 1u);
  return (unsigned short)(u >> 16);
}
__device__ __forceinline__ float b2f(unsigned short s) {
  return __uint_as_float((unsigned int)s << 16);
}
__device__ __forceinline__ float4 b4f(ushort4 v) {
  return make_float4(b2f(v.x), b2f(v.y), b2f(v.z), b2f(v.w));
}
__device__ __forceinline__ ushort4 f4b(float4 v) {
  ushort4 r; r.x = f2b(v.x); r.y = f2b(v.y); r.z = f2b(v.z); r.w = f2b(v.w); return r;
}

// =============== row L2 norm (invn = 1/max(||row||,1e-6)) ===============
__global__ __launch_bounds__(256) void rownorm_kernel(const float* __restrict__ w,
                                                      float* __restrict__ invn, int cols) {
  __shared__ float lds[8];
  size_t r = blockIdx.x;
  const float* row = w + r * (size_t)cols;
  float s = 0.f;
  for (int c = threadIdx.x * 4; c < cols; c += 256 * 4) {
    float4 v = *(const float4*)(row + c);
    s += v.x*v.x + v.y*v.y + v.z*v.z + v.w*v.w;
  }
#pragma unroll
  for (int off = 32; off > 0; off >>= 1) s += __shfl_down(s, off);
  if ((threadIdx.x & 63) == 0) lds[threadIdx.x >> 6] = s;
  __syncthreads();
  if (threadIdx.x == 0) {
    float t = lds[0] + lds[1] + lds[2] + lds[3];
    invn[r] = 1.f / fmaxf(sqrtf(t), 1e-6f);
  }
}

// =============== convert W (f32 [rows][K]) -> bf16 [Npad][K], scaled by invn*alpha ===============
__global__ __launch_bounds__(256) void convert_w_kernel(const float* __restrict__ W,
      const float* __restrict__ invn, float alpha, int rows_valid, int K,
      unsigned short* __restrict__ dst) {
  int n = blockIdx.x;
  unsigned short* drow = dst + (size_t)n * K;
  if (n >= rows_valid) {
    for (int c = threadIdx.x * 4; c < K; c += 1024)
      *(ushort4*)(drow + c) = make_ushort4(0, 0, 0, 0);
    return;
  }
  float s = invn[n] * alpha;
  const float* srow = W + (size_t)n * K;
  for (int c = threadIdx.x * 4; c < K; c += 1024) {
    float4 v = *(const float4*)(srow + c);
    *(ushort4*)(drow + c) = f4b(make_float4(v.x*s, v.y*s, v.z*s, v.w*s));
  }
}

// =============== LayerNorm over last dim (1024) -> bf16 ===============
__global__ __launch_bounds__(256) void layernorm_kernel(const float* __restrict__ u,
      const float* __restrict__ w, const float* __restrict__ b,
      unsigned short* __restrict__ out) {
  __shared__ float lds[16];
  size_t r = blockIdx.x;
  const float* row = u + r * DIM_;
  int d = threadIdx.x * 4;
  float4 v = *(const float4*)(row + d);
  float s = v.x + v.y + v.z + v.w;
  float q = v.x*v.x + v.y*v.y + v.z*v.z + v.w*v.w;
#pragma unroll
  for (int off = 32; off > 0; off >>= 1) { s += __shfl_down(s, off); q += __shfl_down(q, off); }
  int wave = threadIdx.x >> 6;
  if ((threadIdx.x & 63) == 0) { lds[wave] = s; lds[8 + wave] = q; }
  __syncthreads();
  float sa = lds[0]+lds[1]+lds[2]+lds[3];
  float sq = lds[8]+lds[9]+lds[10]+lds[11];
  float mu = sa * (1.f / DIM_);
  float var = sq * (1.f / DIM_) - mu * mu;
  float rstd = rsqrtf(var + 1e-5f);
  float4 wv = *(const float4*)(w + d);
  float4 bv = *(const float4*)(b + d);
  float4 o;
  o.x = (v.x - mu) * rstd * wv.x + bv.x;
  o.y = (v.y - mu) * rstd * wv.y + bv.y;
  o.z = (v.z - mu) * rstd * wv.z + bv.z;
  o.w = (v.w - mu) * rstd * wv.w + bv.w;
  *(ushort4*)(out + r * DIM_ + d) = f4b(o);
}

// =============== bf16 MFMA GEMM (m97 structure): C[m,n] = sum_k A[m,k]*Wb[n,k] ===============
// A: [M][K] bf16 row-major. Wb: [Npad][K] bf16 row-major (pre-scaled by invn*alpha).
// 128x128 tile, BK=32, 256 threads = 4 waves, each wave 64x64 (4x4 frags of 16x16x32).
// Staging via global_load_lds width=16, 2 barriers per K-step.
// EPI 0: split epilogue (z bf16 | xpre bf16 | dtraw f32), skip n>=DPROJ_.
// EPI 1: f32 store to outp with stride Nout.
template<int K, int EPI>
__global__ __launch_bounds__(256) void gemm_mfma(
    const unsigned short* __restrict__ A, const unsigned short* __restrict__ Wb,
    int Nout, unsigned short* __restrict__ zb, unsigned short* __restrict__ xpre,
    float* __restrict__ dtraw, float* __restrict__ outp)
{
  __shared__ __align__(128) unsigned short lds[8192];  // As: 0..4095, Bs: 4096..8191 (ushort idx)
  const int tid  = threadIdx.x;
  const int lane = tid & 63;
  const int w    = tid >> 6;
  const size_t m0 = (size_t)blockIdx.y * 128;
  const int n0 = blockIdx.x * 128;

  f32x4 acc[4][4];
#pragma unroll
  for (int fi = 0; fi < 4; ++fi)
#pragma unroll
    for (int fj = 0; fj < 4; ++fj)
#pragma unroll
      for (int r = 0; r < 4; ++r) acc[fi][fj][r] = 0.f;

  // staging: LDS tile [128 rows][32 k] bf16 (64B rows). linear byte o = q*4096 + tid*16
  // row = o>>6, inrow byte = o&63. global = base + (tile_row0 + row)*K*2 + k0*2 + inrow
  const size_t Kb = (size_t)K * 2;
  const char* ga0 = (const char*)A  + (m0 + (tid >> 2)) * Kb + (tid & 3) * 16;
  const char* ga1 = ga0 + 64 * Kb;
  const char* gb0 = (const char*)Wb + ((size_t)n0 + (tid >> 2)) * Kb + (tid & 3) * 16;
  const char* gb1 = gb0 + 64 * Kb;
  char* ldsb = (char*)lds;
  const int wseg = w * 1024;

  const int mr0 = (w >> 1) * 64, nc0 = (w & 1) * 64;
  // fragment LDS offsets (ushort index)
  const int afrag_base = (mr0 + (lane & 15)) * 32 + (lane >> 4) * 8;
  const int bfrag_base = 4096 + (nc0 + (lane & 15)) * 32 + (lane >> 4) * 8;

  for (int k0 = 0; k0 < (int)Kb; k0 += 64) {
    __builtin_amdgcn_global_load_lds(
        (const __attribute__((address_space(1))) unsigned int*)(ga0 + k0),
        (__attribute__((address_space(3))) unsigned int*)(ldsb + wseg), 16, 0, 0);
    __builtin_amdgcn_global_load_lds(
        (const __attribute__((address_space(1))) unsigned int*)(ga1 + k0),
        (__attribute__((address_space(3))) unsigned int*)(ldsb + 4096 + wseg), 16, 0, 0);
    __builtin_amdgcn_global_load_lds(
        (const __attribute__((address_space(1))) unsigned int*)(gb0 + k0),
        (__attribute__((address_space(3))) unsigned int*)(ldsb + 8192 + wseg), 16, 0, 0);
    __builtin_amdgcn_global_load_lds(
        (const __attribute__((address_space(1))) unsigned int*)(gb1 + k0),
        (__attribute__((address_space(3))) unsigned int*)(ldsb + 12288 + wseg), 16, 0, 0);
    __syncthreads();  // drains vmcnt(0): staged data visible

    bf16x8 a[4], b[4];
#pragma unroll
    for (int fi = 0; fi < 4; ++fi) a[fi] = *(const bf16x8*)&lds[afrag_base + fi * 16 * 32];
#pragma unroll
    for (int fj = 0; fj < 4; ++fj) b[fj] = *(const bf16x8*)&lds[bfrag_base + fj * 16 * 32];
#pragma unroll
    for (int fi = 0; fi < 4; ++fi)
#pragma unroll
      for (int fj = 0; fj < 4; ++fj)
        acc[fi][fj] = __builtin_amdgcn_mfma_f32_16x16x32_bf16(a[fi], b[fj], acc[fi][fj], 0, 0, 0);
    __syncthreads();  // all reads done before next-tile overwrite
  }

  // epilogue: C/D layout col=lane&15, row=(lane>>4)*4+r  [m89-verified]
#pragma unroll
  for (int fj = 0; fj < 4; ++fj) {
    const int n = n0 + nc0 + fj * 16 + (lane & 15);
#pragma unroll
    for (int fi = 0; fi < 4; ++fi) {
#pragma unroll
      for (int r = 0; r < 4; ++r) {
        const size_t m = m0 + mr0 + fi * 16 + (lane >> 4) * 4 + r;
        const float v = acc[fi][fj][r];
        if (EPI == 0) {
          if (n < DINNER_)                   zb[m * DINNER_ + n] = f2b(v);
          else if (n < DINNER_ + CONVD_)     xpre[m * CONVD_ + (n - DINNER_)] = f2b(v);
          else if (n < DPROJ_)               dtraw[m * NH_ + (n - DINNER_ - CONVD_)] = v;
        } else {
          outp[m * (size_t)Nout + n] = v;
        }
      }
    }
  }
}

// =============== depthwise causal conv(4) + SiLU (bf16 in/out) ===============
__global__ __launch_bounds__(256) void conv_silu_kernel(const unsigned short* __restrict__ xpre,
      const float* __restrict__ cw, const float* __restrict__ cb,
      unsigned short* __restrict__ xbc) {
  int c = blockIdx.x * 256 + threadIdx.x;
  if (c >= CONVD_) return;
  int b = blockIdx.z;
  int l0 = blockIdx.y * 64;
  float w0 = cw[c*4+0], w1 = cw[c*4+1], w2 = cw[c*4+2], w3 = cw[c*4+3];
  float bias = cb[c];
  const unsigned short* src = xpre + (size_t)b * SEQL_ * CONVD_ + c;
  float xm3, xm2, xm1;
  if (l0 == 0) { xm3 = 0.f; xm2 = 0.f; xm1 = 0.f; }
  else {
    xm3 = b2f(src[(size_t)(l0-3) * CONVD_]);
    xm2 = b2f(src[(size_t)(l0-2) * CONVD_]);
    xm1 = b2f(src[(size_t)(l0-1) * CONVD_]);
  }
  unsigned short* dst = xbc + ((size_t)b * SEQL_ + l0) * CONVD_ + c;
  for (int t = 0; t < 64; ++t) {
    float x0 = b2f(src[(size_t)(l0 + t) * CONVD_]);
    float v = w0*xm3 + w1*xm2 + w2*xm1 + w3*x0 + bias;
    float sv = v / (1.f + __expf(-v));
    dst[(size_t)t * CONVD_] = f2b(sv);
    xm3 = xm2; xm2 = xm1; xm1 = x0;
  }
}

// =============== dt = softplus(dt_raw + bias); cum = cumsum(dt*A) per chunk ===============
__global__ __launch_bounds__(256) void dtcum_kernel(const float* __restrict__ dtraw,
      const float* __restrict__ dt_bias, const float* __restrict__ A_log,
      float* __restrict__ dtv, float* __restrict__ cum, float* __restrict__ cdec) {
  __shared__ float lds[4];
  int h = blockIdx.x, c = blockIdx.y, b = blockIdx.z;
  int tid = threadIdx.x;
  size_t row = (size_t)b * SEQL_ + c * CHUNKL_ + tid;
  float raw = dtraw[row * NH_ + h] + dt_bias[h];
  float dt = (raw > 20.f) ? raw : log1pf(expf(raw));
  dtv[row * NH_ + h] = dt;
  float v = dt * (-expf(A_log[h]));
  int lane = tid & 63, wave = tid >> 6;
#pragma unroll
  for (int off = 1; off < 64; off <<= 1) {
    float n = __shfl_up(v, off);
    if (lane >= off) v += n;
  }
  if (lane == 63) lds[wave] = v;
  __syncthreads();
  float pre = 0.f;
  for (int w2 = 0; w2 < wave; ++w2) pre += lds[w2];
  v += pre;
  cum[row * NH_ + h] = v;
  if (tid == 255) cdec[((size_t)b * NCHUNK_ + c) * NH_ + h] = __expf(v);
}

// =============== scores[i,j] = C_i . B_j (shared across heads, ngroups=1) ===============
__global__ __launch_bounds__(256) void scores_kernel(const unsigned short* __restrict__ xbc,
                                                     float* __restrict__ scores) {
  __shared__ float Cs[64][64];
  int it = blockIdx.x;  // i-tile of 64
  int c = blockIdx.y, b = blockIdx.z;
  size_t row0 = (size_t)b * SEQL_ + c * CHUNKL_;
  int j = threadIdx.x;
  float Br[64];
  const unsigned short* bp = xbc + (row0 + j) * CONVD_ + DINNER_;
#pragma unroll
  for (int n4 = 0; n4 < 16; ++n4) {
    float4 v = b4f(*(const ushort4*)(bp + n4*4));
    Br[n4*4+0]=v.x; Br[n4*4+1]=v.y; Br[n4*4+2]=v.z; Br[n4*4+3]=v.w;
  }
  {
    int i = threadIdx.x >> 2, q = threadIdx.x & 3;
    const unsigned short* cp = xbc + (row0 + it*64 + i) * CONVD_ + DINNER_ + DSTATE_;
#pragma unroll
    for (int s2 = 0; s2 < 4; ++s2)
      *(float4*)&Cs[i][(q + s2*4)*4] = b4f(*(const ushort4*)(cp + (q + s2*4)*4));
  }
  __syncthreads();
  float* out = scores + ((size_t)b * NCHUNK_ + c) * (CHUNKL_*CHUNKL_) + (size_t)it*64*CHUNKL_ + j;
  for (int i = 0; i < 64; ++i) {
    float s = 0.f;
#pragma unroll
    for (int n = 0; n < 64; ++n) s += Cs[i][n] * Br[n];
    out[(size_t)i * CHUNKL_] = s;
  }
}

// =============== y_intra: y[i,p] = sum_{j<=i} scores[i,j]*exp(cum_i-cum_j)*dt_j * x[j,p] ===============
__global__ __launch_bounds__(256) void yintra_kernel(const unsigned short* __restrict__ xbc,
      const float* __restrict__ scores, const float* __restrict__ dtv,
      const float* __restrict__ cum, unsigned short* __restrict__ y) {
  __shared__ float xs[64][128];
  __shared__ float cumS[256];
  __shared__ float dtS[256];
  int h = blockIdx.x, c = blockIdx.y, b = blockIdx.z;
  size_t row0 = (size_t)b * SEQL_ + c * CHUNKL_;
  int i = threadIdx.x;
  cumS[i] = cum[(row0 + i) * NH_ + h];
  dtS[i]  = dtv[(row0 + i) * NH_ + h];
  float acc[128];
#pragma unroll
  for (int p = 0; p < 128; ++p) acc[p] = 0.f;
  const float* srow = scores + ((size_t)b * NCHUNK_ + c) * (CHUNKL_*CHUNKL_) + (size_t)i * CHUNKL_;
  int wave = i >> 6;
  __syncthreads();
  float cum_i = cumS[i];
  for (int jt = 0; jt < 4; ++jt) {
    {
      int jj = threadIdx.x >> 2, q = threadIdx.x & 3;
      const unsigned short* xp = xbc + (row0 + jt*64 + jj) * CONVD_ + (size_t)h * HD_;
#pragma unroll
      for (int s2 = 0; s2 < 8; ++s2) {
        int p4 = q + s2*4;
        *(float4*)&xs[jj][p4*4] = b4f(*(const ushort4*)(xp + p4*4));
      }
    }
    __syncthreads();
    if (jt <= wave) {
      for (int jj = 0; jj < 64; ++jj) {
        int j = jt*64 + jj;
        if (j <= i) {
          float att = srow[j] * __expf(cum_i - cumS[j]) * dtS[j];
#pragma unroll
          for (int p4 = 0; p4 < 32; ++p4) {
            float4 xv = *(const float4*)&xs[jj][p4*4];
            acc[p4*4+0] += att * xv.x;
            acc[p4*4+1] += att * xv.y;
            acc[p4*4+2] += att * xv.z;
            acc[p4*4+3] += att * xv.w;
          }
        }
      }
    }
    __syncthreads();
  }
  unsigned short* yrow = y + (row0 + i) * DINNER_ + (size_t)h * HD_;
#pragma unroll
  for (int p4 = 0; p4 < 32; ++p4)
    *(ushort4*)(yrow + p4*4) = f4b(make_float4(acc[p4*4+0], acc[p4*4+1], acc[p4*4+2], acc[p4*4+3]));
}

// =============== per-chunk end states: states[h,p,n] = sum_l B[l,n]*dt_l*exp(cum_end-cum_l)*x[l,p] ===============
__global__ __launch_bounds__(128) void states_kernel(const unsigned short* __restrict__ xbc,
      const float* __restrict__ dtv, const float* __restrict__ cum, float* __restrict__ states) {
  __shared__ float coefS[256];
  __shared__ float Bs[64][64];
  int h = blockIdx.x, c = blockIdx.y, b = blockIdx.z;
  size_t row0 = (size_t)b * SEQL_ + c * CHUNKL_;
  int p = threadIdx.x;
  float cum_last = cum[(row0 + 255) * NH_ + h];
  for (int s = p; s < 256; s += 128)
    coefS[s] = dtv[(row0 + s) * NH_ + h] * __expf(cum_last - cum[(row0 + s) * NH_ + h]);
  float acc[64];
#pragma unroll
  for (int n = 0; n < 64; ++n) acc[n] = 0.f;
  for (int lt = 0; lt < 4; ++lt) {
    __syncthreads();
    {
      int lr = p >> 1, q = (p & 1) * 8;
      const unsigned short* bp = xbc + (row0 + lt*64 + lr) * CONVD_ + DINNER_;
#pragma unroll
      for (int s2 = 0; s2 < 8; ++s2)
        *(float4*)&Bs[lr][(q + s2)*4] = b4f(*(const ushort4*)(bp + (q + s2)*4));
    }
    __syncthreads();
    for (int ll = 0; ll < 64; ++ll) {
      int l = lt*64 + ll;
      float xv = b2f(xbc[(row0 + l) * CONVD_ + (size_t)h * HD_ + p]);
      float wv = coefS[l] * xv;
#pragma unroll
      for (int n4 = 0; n4 < 16; ++n4) {
        float4 bv = *(const float4*)&Bs[ll][n4*4];
        acc[n4*4+0] += wv * bv.x; acc[n4*4+1] += wv * bv.y;
        acc[n4*4+2] += wv * bv.z; acc[n4*4+3] += wv * bv.w;
      }
    }
  }
  float* sp = states + ((((size_t)b * NCHUNK_ + c) * NH_ + h) * HD_ + p) * DSTATE_;
#pragma unroll
  for (int n4 = 0; n4 < 16; ++n4)
    *(float4*)(sp + n4*4) = make_float4(acc[n4*4], acc[n4*4+1], acc[n4*4+2], acc[n4*4+3]);
}

// =============== sequential chunk recurrence: prev[c] = prev[c-1]*cdec[c-1] + states[c-1] ===============
__global__ __launch_bounds__(256) void chunkscan_kernel(const float* __restrict__ states,
      const float* __restrict__ cdec, float* __restrict__ prevst) {
  int h = blockIdx.y, b = blockIdx.z;
  int pn = blockIdx.x * 256 + threadIdx.x;  // 0..8191 = p*64+n
  float carry = 0.f;
  for (int c = 0; c < NCHUNK_; ++c) {
    size_t idx = (((size_t)b * NCHUNK_ + c) * NH_ + h) * (HD_*DSTATE_) + pn;
    prevst[idx] = carry;
    carry = carry * cdec[((size_t)b * NCHUNK_ + c) * NH_ + h] + states[idx];
  }
}

// =============== y += exp(cum_l) * (C_l . prev_state[p,:]) + D*x  (bf16 RMW on y) ===============
__global__ __launch_bounds__(128) void yinter_kernel(const unsigned short* __restrict__ xbc,
      const float* __restrict__ prevst, const float* __restrict__ cum,
      const float* __restrict__ Dv, unsigned short* __restrict__ y) {
  __shared__ float ecS[256];
  __shared__ float Cs[64][64];
  int h = blockIdx.x, c = blockIdx.y, b = blockIdx.z;
  size_t row0 = (size_t)b * SEQL_ + c * CHUNKL_;
  int p = threadIdx.x;
  for (int s = p; s < 256; s += 128) ecS[s] = __expf(cum[(row0 + s) * NH_ + h]);
  float S[64];
  const float* sp = prevst + ((((size_t)b * NCHUNK_ + c) * NH_ + h) * HD_ + p) * DSTATE_;
#pragma unroll
  for (int n4 = 0; n4 < 16; ++n4) {
    float4 v = *(const float4*)(sp + n4*4);
    S[n4*4]=v.x; S[n4*4+1]=v.y; S[n4*4+2]=v.z; S[n4*4+3]=v.w;
  }
  float Dh = Dv[h];
  for (int lt = 0; lt < 4; ++lt) {
    __syncthreads();
    {
      int lr = p >> 1, q = (p & 1) * 8;
      const unsigned short* cp = xbc + (row0 + lt*64 + lr) * CONVD_ + DINNER_ + DSTATE_;
#pragma unroll
      for (int s2 = 0; s2 < 8; ++s2)
        *(float4*)&Cs[lr][(q + s2)*4] = b4f(*(const ushort4*)(cp + (q + s2)*4));
    }
    __syncthreads();
    for (int ll = 0; ll < 64; ++ll) {
      int l = lt*64 + ll;
      float dot = 0.f;
#pragma unroll
      for (int n4 = 0; n4 < 16; ++n4) {
        float4 cv = *(const float4*)&Cs[ll][n4*4];
        dot += cv.x*S[n4*4] + cv.y*S[n4*4+1] + cv.z*S[n4*4+2] + cv.w*S[n4*4+3];
      }
      float xv = b2f(xbc[(row0 + l) * CONVD_ + (size_t)h * HD_ + p]);
      size_t yi = (row0 + l) * DINNER_ + (size_t)h * HD_ + p;
      y[yi] = f2b(b2f(y[yi]) + ecS[l] * dot + Dh * xv);
    }
  }
}

// =============== g = y*silu(z); rmsnorm(g)*rms_w  (bf16 in-place over y) ===============
__global__ __launch_bounds__(256) void gate_rms_kernel(const unsigned short* __restrict__ zb,
      const float* __restrict__ rms_w, unsigned short* __restrict__ y) {
  __shared__ float lds[4];
  size_t r = blockIdx.x;
  const unsigned short* zrow = zb + r * DINNER_;
  unsigned short* yrow = y + r * DINNER_;
  int tid = threadIdx.x;
  float g[8];
  float ss = 0.f;
#pragma unroll
  for (int q = 0; q < 2; ++q) {
    int d = q*1024 + tid*4;
    float4 yv = b4f(*(const ushort4*)(yrow + d));
    float4 zv = b4f(*(const ushort4*)(zrow + d));
    float s0 = zv.x / (1.f + __expf(-zv.x));
    float s1 = zv.y / (1.f + __expf(-zv.y));
    float s2 = zv.z / (1.f + __expf(-zv.z));
    float s3 = zv.w / (1.f + __expf(-zv.w));
    g[q*4+0] = yv.x * s0; g[q*4+1] = yv.y * s1;
    g[q*4+2] = yv.z * s2; g[q*4+3] = yv.w * s3;
    ss += g[q*4+0]*g[q*4+0] + g[q*4+1]*g[q*4+1] + g[q*4+2]*g[q*4+2] + g[q*4+3]*g[q*4+3];
  }
#pragma unroll
  for (int off = 32; off > 0; off >>= 1) ss += __shfl_down(ss, off);
  if ((tid & 63) == 0) lds[tid >> 6] = ss;
  __syncthreads();
  float tot = lds[0] + lds[1] + lds[2] + lds[3];
  float scale = rsqrtf(tot * (1.f / DINNER_) + 1e-5f);
#pragma unroll
  for (int q = 0; q < 2; ++q) {
    int d = q*1024 + tid*4;
    float4 wv = *(const float4*)(rms_w + d);
    *(ushort4*)(yrow + d) = f4b(make_float4(g[q*4+0]*scale*wv.x, g[q*4+1]*scale*wv.y,
                                            g[q*4+2]*scale*wv.z, g[q*4+3]*scale*wv.w));
  }
}

extern "C" void kernel_launch(void* const* d_in, const int* in_sizes, int n_in,
                              void* d_out, int out_size, void* d_ws, size_t ws_size,
                              hipStream_t stream) {
  const float* u       = (const float*)d_in[0];
  const float* in_w    = (const float*)d_in[1];
  const float* conv_w  = (const float*)d_in[2];
  const float* conv_b  = (const float*)d_in[3];
  const float* dt_bias = (const float*)d_in[4];
  const float* A_log   = (const float*)d_in[5];
  const float* Dv      = (const float*)d_in[6];
  const float* xn_w    = (const float*)d_in[7];
  const float* xn_b    = (const float*)d_in[8];
  const float* rms_w   = (const float*)d_in[9];
  const float* out_w   = (const float*)d_in[10];
  float* out = (float*)d_out;

  char* wp = (char*)d_ws;
  auto alloc = [&](size_t bytes) -> void* {
    void* p = (void*)wp; wp += (bytes + 1023) & ~(size_t)1023; return p;
  };
  // ~162 MB total with lifetime aliasing:
  unsigned short* xpre = (unsigned short*)alloc((size_t)NROWS_ * CONVD_ * 2);  // 35.7MB; y aliases
  unsigned short* y    = xpre;  // y (8192x2048 bf16) reuses xpre after conv consumes it
  unsigned short* zb   = (unsigned short*)alloc((size_t)NROWS_ * DINNER_ * 2); // 33.6MB
  float* dtraw    = (float*)alloc((size_t)NROWS_ * NH_ * 4);
  unsigned short* xbc  = (unsigned short*)alloc((size_t)NROWS_ * CONVD_ * 2);  // 35.7MB
  float* dtv      = (float*)alloc((size_t)NROWS_ * NH_ * 4);
  float* cum      = (float*)alloc((size_t)NROWS_ * NH_ * 4);
  float* cdec     = (float*)alloc((size_t)BATCH_ * NCHUNK_ * NH_ * 4);
  float* invn_in  = (float*)alloc((size_t)DPROJ_ * 4);
  float* invn_out = (float*)alloc((size_t)DIM_ * 4);
  float* scoresB  = (float*)alloc((size_t)BATCH_ * NCHUNK_ * CHUNKL_ * CHUNKL_ * 4); // 8.4MB
  unsigned short* u_ln = (unsigned short*)alloc((size_t)NROWS_ * DIM_ * 2);    // 16.8MB; states aliases
  float* states   = (float*)u_ln;  // states (16.8MB f32) reuses u_ln after in_proj GEMM
  float* prevst   = (float*)alloc((size_t)BATCH_ * NCHUNK_ * NH_ * HD_ * DSTATE_ * 4); // 16.8MB
  unsigned short* wb_in  = (unsigned short*)alloc((size_t)NPAD_ * DIM_ * 2);   // 8.9MB
  unsigned short* wb_out = (unsigned short*)alloc((size_t)DIM_ * DINNER_ * 2); // 4.2MB

  rownorm_kernel<<<DPROJ_, 256, 0, stream>>>(in_w, invn_in, DIM_);
  rownorm_kernel<<<DIM_, 256, 0, stream>>>(out_w, invn_out, DINNER_);
  convert_w_kernel<<<NPAD_, 256, 0, stream>>>(in_w, invn_in, 0.03125f, DPROJ_, DIM_, wb_in);
  convert_w_kernel<<<DIM_, 256, 0, stream>>>(out_w, invn_out, 1.0f, DIM_, DINNER_, wb_out);
  layernorm_kernel<<<NROWS_, 256, 0, stream>>>(u, xn_w, xn_b, u_ln);
  gemm_mfma<DIM_, 0><<<dim3(NPAD_/128, NROWS_/128), 256, 0, stream>>>(
      u_ln, wb_in, 0, zb, xpre, dtraw, nullptr);
  conv_silu_kernel<<<dim3(9, 64, BATCH_), 256, 0, stream>>>(xpre, conv_w, conv_b, xbc);
  dtcum_kernel<<<dim3(NH_, NCHUNK_, BATCH_), 256, 0, stream>>>(dtraw, dt_bias, A_log, dtv, cum, cdec);
  scores_kernel<<<dim3(4, NCHUNK_, BATCH_), 256, 0, stream>>>(xbc, scoresB);
  yintra_kernel<<<dim3(NH_, NCHUNK_, BATCH_), 256, 0, stream>>>(xbc, scoresB, dtv, cum, y);
  states_kernel<<<dim3(NH_, NCHUNK_, BATCH_), 128, 0, stream>>>(xbc, dtv, cum, states);
  chunkscan_kernel<<<dim3(32, NH_, BATCH_), 256, 0, stream>>>(states, cdec, prevst);
  yinter_kernel<<<dim3(NH_, NCHUNK_, BATCH_), 128, 0, stream>>>(xbc, prevst, cum, Dv, y);
  gate_rms_kernel<<<NROWS_, 256, 0, stream>>>(zb, rms_w, y);
  gemm_mfma<DINNER_, 1><<<dim3(DIM_/128, NROWS_/128), 256, 0, stream>>>(
      y, wb_out, DIM_, nullptr, nullptr, nullptr, out);
}

// Round 6
// 612.823 us; speedup vs baseline: 3.5231x; 1.7394x over previous
//
#include <hip/hip_runtime.h>
#include <hip/hip_bf16.h>
#include <math.h>

// ---- problem constants ----
#define DIM_      1024
#define DPROJ_    4240   // D_IN_PROJ
#define NPAD_     4352   // DPROJ_ padded to 34*128 for MFMA tiles
#define DINNER_   2048
#define CONVD_    2176   // D_INNER + 2*D_STATE
#define NH_       16
#define HD_       128
#define DSTATE_   64
#define CHUNKL_   256
#define NCHUNK_   16     // SEQLEN/CHUNK
#define SEQL_     4096
#define BATCH_    2
#define NROWS_    8192   // BATCH*SEQLEN
#define XT_PITCH  272    // 256 + 16 pad, ushorts; row stride 544B = 34*16B (16B-aligned)

typedef short bf16x8 __attribute__((ext_vector_type(8)));
typedef float f32x4  __attribute__((ext_vector_type(4)));

// ---- bf16 <-> f32 helpers (bit-level, round-to-nearest-even) ----
__device__ __forceinline__ unsigned short f2b(float f) {
  unsigned int u = __float_as_uint(f);
  u += 0x7fffu + ((u >> 16) & 1u);
  return (unsigned short)(u >> 16);
}
__device__ __forceinline__ float b2f(unsigned short s) {
  return __uint_as_float((unsigned int)s << 16);
}
__device__ __forceinline__ float4 b4f(ushort4 v) {
  return make_float4(b2f(v.x), b2f(v.y), b2f(v.z), b2f(v.w));
}
__device__ __forceinline__ ushort4 f4b(float4 v) {
  ushort4 r; r.x = f2b(v.x); r.y = f2b(v.y); r.z = f2b(v.z); r.w = f2b(v.w); return r;
}

// =============== row L2 norm (invn = 1/max(||row||,1e-6)) ===============
__global__ __launch_bounds__(256) void rownorm_kernel(const float* __restrict__ w,
                                                      float* __restrict__ invn, int cols) {
  __shared__ float lds[8];
  size_t r = blockIdx.x;
  const float* row = w + r * (size_t)cols;
  float s = 0.f;
  for (int c = threadIdx.x * 4; c < cols; c += 256 * 4) {
    float4 v = *(const float4*)(row + c);
    s += v.x*v.x + v.y*v.y + v.z*v.z + v.w*v.w;
  }
#pragma unroll
  for (int off = 32; off > 0; off >>= 1) s += __shfl_down(s, off);
  if ((threadIdx.x & 63) == 0) lds[threadIdx.x >> 6] = s;
  __syncthreads();
  if (threadIdx.x == 0) {
    float t = lds[0] + lds[1] + lds[2] + lds[3];
    invn[r] = 1.f / fmaxf(sqrtf(t), 1e-6f);
  }
}

// =============== convert W (f32 [rows][K]) -> bf16 [Npad][K], scaled by invn*alpha ===============
__global__ __launch_bounds__(256) void convert_w_kernel(const float* __restrict__ W,
      const float* __restrict__ invn, float alpha, int rows_valid, int K,
      unsigned short* __restrict__ dst) {
  int n = blockIdx.x;
  unsigned short* drow = dst + (size_t)n * K;
  if (n >= rows_valid) {
    for (int c = threadIdx.x * 4; c < K; c += 1024)
      *(ushort4*)(drow + c) = make_ushort4(0, 0, 0, 0);
    return;
  }
  float s = invn[n] * alpha;
  const float* srow = W + (size_t)n * K;
  for (int c = threadIdx.x * 4; c < K; c += 1024) {
    float4 v = *(const float4*)(srow + c);
    *(ushort4*)(drow + c) = f4b(make_float4(v.x*s, v.y*s, v.z*s, v.w*s));
  }
}

// =============== LayerNorm over last dim (1024) -> bf16 ===============
__global__ __launch_bounds__(256) void layernorm_kernel(const float* __restrict__ u,
      const float* __restrict__ w, const float* __restrict__ b,
      unsigned short* __restrict__ out) {
  __shared__ float lds[16];
  size_t r = blockIdx.x;
  const float* row = u + r * DIM_;
  int d = threadIdx.x * 4;
  float4 v = *(const float4*)(row + d);
  float s = v.x + v.y + v.z + v.w;
  float q = v.x*v.x + v.y*v.y + v.z*v.z + v.w*v.w;
#pragma unroll
  for (int off = 32; off > 0; off >>= 1) { s += __shfl_down(s, off); q += __shfl_down(q, off); }
  int wave = threadIdx.x >> 6;
  if ((threadIdx.x & 63) == 0) { lds[wave] = s; lds[8 + wave] = q; }
  __syncthreads();
  float sa = lds[0]+lds[1]+lds[2]+lds[3];
  float sq = lds[8]+lds[9]+lds[10]+lds[11];
  float mu = sa * (1.f / DIM_);
  float var = sq * (1.f / DIM_) - mu * mu;
  float rstd = rsqrtf(var + 1e-5f);
  float4 wv = *(const float4*)(w + d);
  float4 bv = *(const float4*)(b + d);
  float4 o;
  o.x = (v.x - mu) * rstd * wv.x + bv.x;
  o.y = (v.y - mu) * rstd * wv.y + bv.y;
  o.z = (v.z - mu) * rstd * wv.z + bv.z;
  o.w = (v.w - mu) * rstd * wv.w + bv.w;
  *(ushort4*)(out + r * DIM_ + d) = f4b(o);
}

// =============== bf16 MFMA GEMM (m97 structure): C[m,n] = sum_k A[m,k]*Wb[n,k] ===============
template<int K, int EPI>
__global__ __launch_bounds__(256) void gemm_mfma(
    const unsigned short* __restrict__ A, const unsigned short* __restrict__ Wb,
    int Nout, unsigned short* __restrict__ zb, unsigned short* __restrict__ xpre,
    float* __restrict__ dtraw, float* __restrict__ outp)
{
  __shared__ __align__(128) unsigned short lds[8192];  // As: 0..4095, Bs: 4096..8191 (ushort idx)
  const int tid  = threadIdx.x;
  const int lane = tid & 63;
  const int w    = tid >> 6;
  const size_t m0 = (size_t)blockIdx.y * 128;
  const int n0 = blockIdx.x * 128;

  f32x4 acc[4][4];
#pragma unroll
  for (int fi = 0; fi < 4; ++fi)
#pragma unroll
    for (int fj = 0; fj < 4; ++fj)
#pragma unroll
      for (int r = 0; r < 4; ++r) acc[fi][fj][r] = 0.f;

  const size_t Kb = (size_t)K * 2;
  const char* ga0 = (const char*)A  + (m0 + (tid >> 2)) * Kb + (tid & 3) * 16;
  const char* ga1 = ga0 + 64 * Kb;
  const char* gb0 = (const char*)Wb + ((size_t)n0 + (tid >> 2)) * Kb + (tid & 3) * 16;
  const char* gb1 = gb0 + 64 * Kb;
  char* ldsb = (char*)lds;
  const int wseg = w * 1024;

  const int mr0 = (w >> 1) * 64, nc0 = (w & 1) * 64;
  const int afrag_base = (mr0 + (lane & 15)) * 32 + (lane >> 4) * 8;
  const int bfrag_base = 4096 + (nc0 + (lane & 15)) * 32 + (lane >> 4) * 8;

  for (int k0 = 0; k0 < (int)Kb; k0 += 64) {
    __builtin_amdgcn_global_load_lds(
        (const __attribute__((address_space(1))) unsigned int*)(ga0 + k0),
        (__attribute__((address_space(3))) unsigned int*)(ldsb + wseg), 16, 0, 0);
    __builtin_amdgcn_global_load_lds(
        (const __attribute__((address_space(1))) unsigned int*)(ga1 + k0),
        (__attribute__((address_space(3))) unsigned int*)(ldsb + 4096 + wseg), 16, 0, 0);
    __builtin_amdgcn_global_load_lds(
        (const __attribute__((address_space(1))) unsigned int*)(gb0 + k0),
        (__attribute__((address_space(3))) unsigned int*)(ldsb + 8192 + wseg), 16, 0, 0);
    __builtin_amdgcn_global_load_lds(
        (const __attribute__((address_space(1))) unsigned int*)(gb1 + k0),
        (__attribute__((address_space(3))) unsigned int*)(ldsb + 12288 + wseg), 16, 0, 0);
    __syncthreads();

    bf16x8 a[4], b[4];
#pragma unroll
    for (int fi = 0; fi < 4; ++fi) a[fi] = *(const bf16x8*)&lds[afrag_base + fi * 16 * 32];
#pragma unroll
    for (int fj = 0; fj < 4; ++fj) b[fj] = *(const bf16x8*)&lds[bfrag_base + fj * 16 * 32];
#pragma unroll
    for (int fi = 0; fi < 4; ++fi)
#pragma unroll
      for (int fj = 0; fj < 4; ++fj)
        acc[fi][fj] = __builtin_amdgcn_mfma_f32_16x16x32_bf16(a[fi], b[fj], acc[fi][fj], 0, 0, 0);
    __syncthreads();
  }

#pragma unroll
  for (int fj = 0; fj < 4; ++fj) {
    const int n = n0 + nc0 + fj * 16 + (lane & 15);
#pragma unroll
    for (int fi = 0; fi < 4; ++fi) {
#pragma unroll
      for (int r = 0; r < 4; ++r) {
        const size_t m = m0 + mr0 + fi * 16 + (lane >> 4) * 4 + r;
        const float v = acc[fi][fj][r];
        if (EPI == 0) {
          if (n < DINNER_)                   zb[m * DINNER_ + n] = f2b(v);
          else if (n < DINNER_ + CONVD_)     xpre[m * CONVD_ + (n - DINNER_)] = f2b(v);
          else if (n < DPROJ_)               dtraw[m * NH_ + (n - DINNER_ - CONVD_)] = v;
        } else {
          outp[m * (size_t)Nout + n] = v;
        }
      }
    }
  }
}

// =============== depthwise causal conv(4) + SiLU (bf16 in/out) ===============
__global__ __launch_bounds__(256) void conv_silu_kernel(const unsigned short* __restrict__ xpre,
      const float* __restrict__ cw, const float* __restrict__ cb,
      unsigned short* __restrict__ xbc) {
  int c = blockIdx.x * 256 + threadIdx.x;
  if (c >= CONVD_) return;
  int b = blockIdx.z;
  int l0 = blockIdx.y * 64;
  float w0 = cw[c*4+0], w1 = cw[c*4+1], w2 = cw[c*4+2], w3 = cw[c*4+3];
  float bias = cb[c];
  const unsigned short* src = xpre + (size_t)b * SEQL_ * CONVD_ + c;
  float xm3, xm2, xm1;
  if (l0 == 0) { xm3 = 0.f; xm2 = 0.f; xm1 = 0.f; }
  else {
    xm3 = b2f(src[(size_t)(l0-3) * CONVD_]);
    xm2 = b2f(src[(size_t)(l0-2) * CONVD_]);
    xm1 = b2f(src[(size_t)(l0-1) * CONVD_]);
  }
  unsigned short* dst = xbc + ((size_t)b * SEQL_ + l0) * CONVD_ + c;
  for (int t = 0; t < 64; ++t) {
    float x0 = b2f(src[(size_t)(l0 + t) * CONVD_]);
    float v = w0*xm3 + w1*xm2 + w2*xm1 + w3*x0 + bias;
    float sv = v / (1.f + __expf(-v));
    dst[(size_t)t * CONVD_] = f2b(sv);
    xm3 = xm2; xm2 = xm1; xm1 = x0;
  }
}

// =============== dt = softplus(dt_raw + bias); cum = cumsum(dt*A) per chunk ===============
__global__ __launch_bounds__(256) void dtcum_kernel(const float* __restrict__ dtraw,
      const float* __restrict__ dt_bias, const float* __restrict__ A_log,
      float* __restrict__ dtv, float* __restrict__ cum, float* __restrict__ cdec) {
  __shared__ float lds[4];
  int h = blockIdx.x, c = blockIdx.y, b = blockIdx.z;
  int tid = threadIdx.x;
  size_t row = (size_t)b * SEQL_ + c * CHUNKL_ + tid;
  float raw = dtraw[row * NH_ + h] + dt_bias[h];
  float dt = (raw > 20.f) ? raw : log1pf(expf(raw));
  dtv[row * NH_ + h] = dt;
  float v = dt * (-expf(A_log[h]));
  int lane = tid & 63, wave = tid >> 6;
#pragma unroll
  for (int off = 1; off < 64; off <<= 1) {
    float n = __shfl_up(v, off);
    if (lane >= off) v += n;
  }
  if (lane == 63) lds[wave] = v;
  __syncthreads();
  float pre = 0.f;
  for (int w2 = 0; w2 < wave; ++w2) pre += lds[w2];
  v += pre;
  cum[row * NH_ + h] = v;
  if (tid == 255) cdec[((size_t)b * NCHUNK_ + c) * NH_ + h] = __expf(v);
}

// =============== scores[i,j] = C_i . B_j (shared across heads, ngroups=1) ===============
__global__ __launch_bounds__(256) void scores_kernel(const unsigned short* __restrict__ xbc,
                                                     float* __restrict__ scores) {
  __shared__ float Cs[64][64];
  int it = blockIdx.x;  // i-tile of 64
  int c = blockIdx.y, b = blockIdx.z;
  size_t row0 = (size_t)b * SEQL_ + c * CHUNKL_;
  int j = threadIdx.x;
  float Br[64];
  const unsigned short* bp = xbc + (row0 + j) * CONVD_ + DINNER_;
#pragma unroll
  for (int n4 = 0; n4 < 16; ++n4) {
    float4 v = b4f(*(const ushort4*)(bp + n4*4));
    Br[n4*4+0]=v.x; Br[n4*4+1]=v.y; Br[n4*4+2]=v.z; Br[n4*4+3]=v.w;
  }
  {
    int i = threadIdx.x >> 2, q = threadIdx.x & 3;
    const unsigned short* cp = xbc + (row0 + it*64 + i) * CONVD_ + DINNER_ + DSTATE_;
#pragma unroll
    for (int s2 = 0; s2 < 4; ++s2)
      *(float4*)&Cs[i][(q + s2*4)*4] = b4f(*(const ushort4*)(cp + (q + s2*4)*4));
  }
  __syncthreads();
  float* out = scores + ((size_t)b * NCHUNK_ + c) * (CHUNKL_*CHUNKL_) + (size_t)it*64*CHUNKL_ + j;
  for (int i = 0; i < 64; ++i) {
    float s = 0.f;
#pragma unroll
    for (int n = 0; n < 64; ++n) s += Cs[i][n] * Br[n];
    out[(size_t)i * CHUNKL_] = s;
  }
}

// =============== FUSED SSD: y = (att @ x) + (exp(cum)·C @ prevst^T) + D*x  (MFMA) ===============
// Grid (h, c, b), 256 thr = 4 waves. Wave w owns i-rows [w*64, w*64+64), all 128 p.
// att[i][j] = scores[i][j]*exp(cum_i-cum_j)*dt_j (j<=i), built per-lane in A-frag layout.
__global__ __launch_bounds__(256, 2) void ssd_fused_kernel(
    const unsigned short* __restrict__ xbc, const float* __restrict__ scores,
    const float* __restrict__ dtv, const float* __restrict__ cum,
    const float* __restrict__ prevst, const float* __restrict__ Dv,
    unsigned short* __restrict__ y)
{
  __shared__ unsigned short xT[128 * XT_PITCH];  // xT[p][j] = x[j][p]  (69.6 KB)
  __shared__ float cumS[256];
  __shared__ float dtS[256];
  const int h = blockIdx.x, c = blockIdx.y, b = blockIdx.z;
  const size_t row0 = (size_t)b * SEQL_ + c * CHUNKL_;
  const int tid = threadIdx.x;
  const int lane = tid & 63;
  const int w = tid >> 6;
  const int i0 = w * 64;

  // stage cum/dt for this (b,c,h)
  cumS[tid] = cum[(row0 + tid) * NH_ + h];
  dtS[tid]  = dtv[(row0 + tid) * NH_ + h];

  // stage xT: thread t owns row j=t; scalar u16 transposed writes (one-time)
  {
    const unsigned short* xp = xbc + (row0 + tid) * CONVD_ + (size_t)h * HD_;
#pragma unroll
    for (int q = 0; q < 16; ++q) {
      ushort4 v = *(const ushort4*)(xp + q * 8);      // wait: ushort4 = 4 elems
      xT[(q*8+0) * XT_PITCH + tid] = v.x;             // handled below in 8-elem steps
      xT[(q*8+1) * XT_PITCH + tid] = v.y;
      xT[(q*8+2) * XT_PITCH + tid] = v.z;
      xT[(q*8+3) * XT_PITCH + tid] = v.w;
      ushort4 v2 = *(const ushort4*)(xp + q * 8 + 4);
      xT[(q*8+4) * XT_PITCH + tid] = v2.x;
      xT[(q*8+5) * XT_PITCH + tid] = v2.y;
      xT[(q*8+6) * XT_PITCH + tid] = v2.z;
      xT[(q*8+7) * XT_PITCH + tid] = v2.w;
    }
  }
  __syncthreads();

  f32x4 acc[4][8];
#pragma unroll
  for (int fi = 0; fi < 4; ++fi)
#pragma unroll
    for (int fj = 0; fj < 8; ++fj)
#pragma unroll
      for (int r = 0; r < 4; ++r) acc[fi][fj][r] = 0.f;

  float cum_i[4];
#pragma unroll
  for (int fi = 0; fi < 4; ++fi) cum_i[fi] = cumS[i0 + fi*16 + (lane & 15)];

  const float* sc_bc = scores + ((size_t)b * NCHUNK_ + c) * (CHUNKL_*CHUNKL_);
  const int nsteps = 2*w + 2;

  for (int jt = 0; jt < nsteps; ++jt) {
    const int j0 = jt*32 + (lane >> 4) * 8;
    float cj[8], dj[8];
    *(float4*)(cj)   = *(const float4*)&cumS[j0];
    *(float4*)(cj+4) = *(const float4*)&cumS[j0 + 4];
    *(float4*)(dj)   = *(const float4*)&dtS[j0];
    *(float4*)(dj+4) = *(const float4*)&dtS[j0 + 4];
    const bool diag = (jt >= 2*w);

    bf16x8 a[4];
#pragma unroll
    for (int fi = 0; fi < 4; ++fi) {
      const int irow = i0 + fi*16 + (lane & 15);
      const float* srow = sc_bc + (size_t)irow * CHUNKL_ + j0;
      float sv[8];
      *(float4*)(sv)   = *(const float4*)srow;
      *(float4*)(sv+4) = *(const float4*)(srow + 4);
      union { bf16x8 v; unsigned short u[8]; } pa;
#pragma unroll
      for (int e = 0; e < 8; ++e) {
        float val = sv[e] * __expf(cum_i[fi] - cj[e]) * dj[e];
        if (diag) val = ((j0 + e) <= irow) ? val : 0.f;
        pa.u[e] = f2b(val);
      }
      a[fi] = pa.v;
    }

    bf16x8 bf[8];
#pragma unroll
    for (int fj = 0; fj < 8; ++fj) {
      const int p = fj*16 + (lane & 15);
      bf[fj] = *(const bf16x8*)&xT[p * XT_PITCH + j0];
    }
#pragma unroll
    for (int fi = 0; fi < 4; ++fi)
#pragma unroll
      for (int fj = 0; fj < 8; ++fj)
        acc[fi][fj] = __builtin_amdgcn_mfma_f32_16x16x32_bf16(a[fi], bf[fj], acc[fi][fj], 0, 0, 0);
  }

  // ---- y_inter: acc += (exp(cum_i)*C) @ prevst^T  (K = 64, 2 steps) ----
  {
    float ec[4];
#pragma unroll
    for (int fi = 0; fi < 4; ++fi) ec[fi] = __expf(cum_i[fi]);
    const float* pbase = prevst + (((size_t)b * NCHUNK_ + c) * NH_ + h) * (HD_ * DSTATE_);
#pragma unroll
    for (int ks = 0; ks < 2; ++ks) {
      const int nk = ks*32 + (lane >> 4) * 8;
      bf16x8 a2[4];
#pragma unroll
      for (int fi = 0; fi < 4; ++fi) {
        const int irow = i0 + fi*16 + (lane & 15);
        const unsigned short* cp = xbc + (row0 + irow) * CONVD_ + DINNER_ + DSTATE_ + nk;
        union { bf16x8 v; unsigned short u[8]; } pin, pout;
        pin.v = *(const bf16x8*)cp;
#pragma unroll
        for (int e = 0; e < 8; ++e) pout.u[e] = f2b(b2f(pin.u[e]) * ec[fi]);
        a2[fi] = pout.v;
      }
      bf16x8 b2[8];
#pragma unroll
      for (int fj = 0; fj < 8; ++fj) {
        const int p = fj*16 + (lane & 15);
        const float* pp = pbase + (size_t)p * DSTATE_ + nk;
        float pv[8];
        *(float4*)(pv)   = *(const float4*)pp;
        *(float4*)(pv+4) = *(const float4*)(pp + 4);
        union { bf16x8 v; unsigned short u[8]; } pb;
#pragma unroll
        for (int e = 0; e < 8; ++e) pb.u[e] = f2b(pv[e]);
        b2[fj] = pb.v;
      }
#pragma unroll
      for (int fi = 0; fi < 4; ++fi)
#pragma unroll
        for (int fj = 0; fj < 8; ++fj)
          acc[fi][fj] = __builtin_amdgcn_mfma_f32_16x16x32_bf16(a2[fi], b2[fj], acc[fi][fj], 0, 0, 0);
    }
  }

  // ---- epilogue: + D*x, store bf16 ----
  const float Dh = Dv[h];
#pragma unroll
  for (int fi = 0; fi < 4; ++fi) {
#pragma unroll
    for (int fj = 0; fj < 8; ++fj) {
      const int p = fj*16 + (lane & 15);
#pragma unroll
      for (int r = 0; r < 4; ++r) {
        const int irow = i0 + fi*16 + (lane >> 4) * 4 + r;
        const float xv = b2f(xT[p * XT_PITCH + irow]);
        y[(row0 + irow) * DINNER_ + (size_t)h * HD_ + p] = f2b(acc[fi][fj][r] + Dh * xv);
      }
    }
  }
}

// =============== per-chunk end states: states[h,p,n] = sum_l B[l,n]*dt_l*exp(cum_end-cum_l)*x[l,p] ===============
__global__ __launch_bounds__(128) void states_kernel(const unsigned short* __restrict__ xbc,
      const float* __restrict__ dtv, const float* __restrict__ cum, float* __restrict__ states) {
  __shared__ float coefS[256];
  __shared__ float Bs[64][64];
  int h = blockIdx.x, c = blockIdx.y, b = blockIdx.z;
  size_t row0 = (size_t)b * SEQL_ + c * CHUNKL_;
  int p = threadIdx.x;
  float cum_last = cum[(row0 + 255) * NH_ + h];
  for (int s = p; s < 256; s += 128)
    coefS[s] = dtv[(row0 + s) * NH_ + h] * __expf(cum_last - cum[(row0 + s) * NH_ + h]);
  float acc[64];
#pragma unroll
  for (int n = 0; n < 64; ++n) acc[n] = 0.f;
  for (int lt = 0; lt < 4; ++lt) {
    __syncthreads();
    {
      int lr = p >> 1, q = (p & 1) * 8;
      const unsigned short* bp = xbc + (row0 + lt*64 + lr) * CONVD_ + DINNER_;
#pragma unroll
      for (int s2 = 0; s2 < 8; ++s2)
        *(float4*)&Bs[lr][(q + s2)*4] = b4f(*(const ushort4*)(bp + (q + s2)*4));
    }
    __syncthreads();
    for (int ll = 0; ll < 64; ++ll) {
      int l = lt*64 + ll;
      float xv = b2f(xbc[(row0 + l) * CONVD_ + (size_t)h * HD_ + p]);
      float wv = coefS[l] * xv;
#pragma unroll
      for (int n4 = 0; n4 < 16; ++n4) {
        float4 bv = *(const float4*)&Bs[ll][n4*4];
        acc[n4*4+0] += wv * bv.x; acc[n4*4+1] += wv * bv.y;
        acc[n4*4+2] += wv * bv.z; acc[n4*4+3] += wv * bv.w;
      }
    }
  }
  float* sp = states + ((((size_t)b * NCHUNK_ + c) * NH_ + h) * HD_ + p) * DSTATE_;
#pragma unroll
  for (int n4 = 0; n4 < 16; ++n4)
    *(float4*)(sp + n4*4) = make_float4(acc[n4*4], acc[n4*4+1], acc[n4*4+2], acc[n4*4+3]);
}

// =============== sequential chunk recurrence: prev[c] = prev[c-1]*cdec[c-1] + states[c-1] ===============
__global__ __launch_bounds__(256) void chunkscan_kernel(const float* __restrict__ states,
      const float* __restrict__ cdec, float* __restrict__ prevst) {
  int h = blockIdx.y, b = blockIdx.z;
  int pn = blockIdx.x * 256 + threadIdx.x;  // 0..8191 = p*64+n
  float carry = 0.f;
  for (int c = 0; c < NCHUNK_; ++c) {
    size_t idx = (((size_t)b * NCHUNK_ + c) * NH_ + h) * (HD_*DSTATE_) + pn;
    prevst[idx] = carry;
    carry = carry * cdec[((size_t)b * NCHUNK_ + c) * NH_ + h] + states[idx];
  }
}

// =============== g = y*silu(z); rmsnorm(g)*rms_w  (bf16 in-place over y) ===============
__global__ __launch_bounds__(256) void gate_rms_kernel(const unsigned short* __restrict__ zb,
      const float* __restrict__ rms_w, unsigned short* __restrict__ y) {
  __shared__ float lds[4];
  size_t r = blockIdx.x;
  const unsigned short* zrow = zb + r * DINNER_;
  unsigned short* yrow = y + r * DINNER_;
  int tid = threadIdx.x;
  float g[8];
  float ss = 0.f;
#pragma unroll
  for (int q = 0; q < 2; ++q) {
    int d = q*1024 + tid*4;
    float4 yv = b4f(*(const ushort4*)(yrow + d));
    float4 zv = b4f(*(const ushort4*)(zrow + d));
    float s0 = zv.x / (1.f + __expf(-zv.x));
    float s1 = zv.y / (1.f + __expf(-zv.y));
    float s2 = zv.z / (1.f + __expf(-zv.z));
    float s3 = zv.w / (1.f + __expf(-zv.w));
    g[q*4+0] = yv.x * s0; g[q*4+1] = yv.y * s1;
    g[q*4+2] = yv.z * s2; g[q*4+3] = yv.w * s3;
    ss += g[q*4+0]*g[q*4+0] + g[q*4+1]*g[q*4+1] + g[q*4+2]*g[q*4+2] + g[q*4+3]*g[q*4+3];
  }
#pragma unroll
  for (int off = 32; off > 0; off >>= 1) ss += __shfl_down(ss, off);
  if ((tid & 63) == 0) lds[tid >> 6] = ss;
  __syncthreads();
  float tot = lds[0] + lds[1] + lds[2] + lds[3];
  float scale = rsqrtf(tot * (1.f / DINNER_) + 1e-5f);
#pragma unroll
  for (int q = 0; q < 2; ++q) {
    int d = q*1024 + tid*4;
    float4 wv = *(const float4*)(rms_w + d);
    *(ushort4*)(yrow + d) = f4b(make_float4(g[q*4+0]*scale*wv.x, g[q*4+1]*scale*wv.y,
                                            g[q*4+2]*scale*wv.z, g[q*4+3]*scale*wv.w));
  }
}

extern "C" void kernel_launch(void* const* d_in, const int* in_sizes, int n_in,
                              void* d_out, int out_size, void* d_ws, size_t ws_size,
                              hipStream_t stream) {
  const float* u       = (const float*)d_in[0];
  const float* in_w    = (const float*)d_in[1];
  const float* conv_w  = (const float*)d_in[2];
  const float* conv_b  = (const float*)d_in[3];
  const float* dt_bias = (const float*)d_in[4];
  const float* A_log   = (const float*)d_in[5];
  const float* Dv      = (const float*)d_in[6];
  const float* xn_w    = (const float*)d_in[7];
  const float* xn_b    = (const float*)d_in[8];
  const float* rms_w   = (const float*)d_in[9];
  const float* out_w   = (const float*)d_in[10];
  float* out = (float*)d_out;

  char* wp = (char*)d_ws;
  auto alloc = [&](size_t bytes) -> void* {
    void* p = (void*)wp; wp += (bytes + 1023) & ~(size_t)1023; return p;
  };
  unsigned short* xpre = (unsigned short*)alloc((size_t)NROWS_ * CONVD_ * 2);  // 35.7MB; y aliases
  unsigned short* y    = xpre;  // y (8192x2048 bf16) reuses xpre after conv consumes it
  unsigned short* zb   = (unsigned short*)alloc((size_t)NROWS_ * DINNER_ * 2); // 33.6MB
  float* dtraw    = (float*)alloc((size_t)NROWS_ * NH_ * 4);
  unsigned short* xbc  = (unsigned short*)alloc((size_t)NROWS_ * CONVD_ * 2);  // 35.7MB
  float* dtv      = (float*)alloc((size_t)NROWS_ * NH_ * 4);
  float* cum      = (float*)alloc((size_t)NROWS_ * NH_ * 4);
  float* cdec     = (float*)alloc((size_t)BATCH_ * NCHUNK_ * NH_ * 4);
  float* invn_in  = (float*)alloc((size_t)DPROJ_ * 4);
  float* invn_out = (float*)alloc((size_t)DIM_ * 4);
  float* scoresB  = (float*)alloc((size_t)BATCH_ * NCHUNK_ * CHUNKL_ * CHUNKL_ * 4); // 8.4MB
  unsigned short* u_ln = (unsigned short*)alloc((size_t)NROWS_ * DIM_ * 2);    // 16.8MB; states aliases
  float* states   = (float*)u_ln;  // states (16.8MB f32) reuses u_ln after in_proj GEMM
  float* prevst   = (float*)alloc((size_t)BATCH_ * NCHUNK_ * NH_ * HD_ * DSTATE_ * 4); // 16.8MB
  unsigned short* wb_in  = (unsigned short*)alloc((size_t)NPAD_ * DIM_ * 2);   // 8.9MB
  unsigned short* wb_out = (unsigned short*)alloc((size_t)DIM_ * DINNER_ * 2); // 4.2MB

  rownorm_kernel<<<DPROJ_, 256, 0, stream>>>(in_w, invn_in, DIM_);
  rownorm_kernel<<<DIM_, 256, 0, stream>>>(out_w, invn_out, DINNER_);
  convert_w_kernel<<<NPAD_, 256, 0, stream>>>(in_w, invn_in, 0.03125f, DPROJ_, DIM_, wb_in);
  convert_w_kernel<<<DIM_, 256, 0, stream>>>(out_w, invn_out, 1.0f, DIM_, DINNER_, wb_out);
  layernorm_kernel<<<NROWS_, 256, 0, stream>>>(u, xn_w, xn_b, u_ln);
  gemm_mfma<DIM_, 0><<<dim3(NPAD_/128, NROWS_/128), 256, 0, stream>>>(
      u_ln, wb_in, 0, zb, xpre, dtraw, nullptr);
  conv_silu_kernel<<<dim3(9, 64, BATCH_), 256, 0, stream>>>(xpre, conv_w, conv_b, xbc);
  dtcum_kernel<<<dim3(NH_, NCHUNK_, BATCH_), 256, 0, stream>>>(dtraw, dt_bias, A_log, dtv, cum, cdec);
  scores_kernel<<<dim3(4, NCHUNK_, BATCH_), 256, 0, stream>>>(xbc, scoresB);
  states_kernel<<<dim3(NH_, NCHUNK_, BATCH_), 128, 0, stream>>>(xbc, dtv, cum, states);
  chunkscan_kernel<<<dim3(32, NH_, BATCH_), 256, 0, stream>>>(states, cdec, prevst);
  ssd_fused_kernel<<<dim3(NH_, NCHUNK_, BATCH_), 256, 0, stream>>>(
      xbc, scoresB, dtv, cum, prevst, Dv, y);
  gate_rms_kernel<<<NROWS_, 256, 0, stream>>>(zb, rms_w, y);
  gemm_mfma<DINNER_, 1><<<dim3(DIM_/128, NROWS_/128), 256, 0, stream>>>(
      y, wb_out, DIM_, nullptr, nullptr, nullptr, out);
}

// Round 7
// 450.626 us; speedup vs baseline: 4.7912x; 1.3599x over previous
//
#include <hip/hip_runtime.h>
#include <hip/hip_bf16.h>
#include <math.h>

// ---- problem constants ----
#define DIM_      1024
#define DPROJ_    4240   // D_IN_PROJ
#define NPAD_     4352   // DPROJ_ padded to 34*128 for MFMA tiles
#define DINNER_   2048
#define CONVD_    2176   // D_INNER + 2*D_STATE
#define NH_       16
#define HD_       128
#define DSTATE_   64
#define CHUNKL_   256
#define NCHUNK_   16     // SEQLEN/CHUNK
#define SEQL_     4096
#define BATCH_    2
#define NROWS_    8192   // BATCH*SEQLEN
#define XT_PITCH  272    // ssd_fused x-transpose pitch (544B rows, 16B-aligned)
#define ST_PITCH  264    // states staging pitch (528B = 33*16B: aligned + 4-bank row rotation)

typedef short bf16x8 __attribute__((ext_vector_type(8)));
typedef float f32x4  __attribute__((ext_vector_type(4)));

// ---- bf16 <-> f32 helpers (bit-level, round-to-nearest-even) ----
__device__ __forceinline__ unsigned short f2b(float f) {
  unsigned int u = __float_as_uint(f);
  u += 0x7fffu + ((u >> 16) & 1u);
  return (unsigned short)(u >> 16);
}
__device__ __forceinline__ float b2f(unsigned short s) {
  return __uint_as_float((unsigned int)s << 16);
}
__device__ __forceinline__ float4 b4f(ushort4 v) {
  return make_float4(b2f(v.x), b2f(v.y), b2f(v.z), b2f(v.w));
}
__device__ __forceinline__ ushort4 f4b(float4 v) {
  ushort4 r; r.x = f2b(v.x); r.y = f2b(v.y); r.z = f2b(v.z); r.w = f2b(v.w); return r;
}

// =============== row L2 norm (invn = 1/max(||row||,1e-6)) ===============
__global__ __launch_bounds__(256) void rownorm_kernel(const float* __restrict__ w,
                                                      float* __restrict__ invn, int cols) {
  __shared__ float lds[8];
  size_t r = blockIdx.x;
  const float* row = w + r * (size_t)cols;
  float s = 0.f;
  for (int c = threadIdx.x * 4; c < cols; c += 256 * 4) {
    float4 v = *(const float4*)(row + c);
    s += v.x*v.x + v.y*v.y + v.z*v.z + v.w*v.w;
  }
#pragma unroll
  for (int off = 32; off > 0; off >>= 1) s += __shfl_down(s, off);
  if ((threadIdx.x & 63) == 0) lds[threadIdx.x >> 6] = s;
  __syncthreads();
  if (threadIdx.x == 0) {
    float t = lds[0] + lds[1] + lds[2] + lds[3];
    invn[r] = 1.f / fmaxf(sqrtf(t), 1e-6f);
  }
}

// =============== convert W (f32 [rows][K]) -> bf16 [Npad][K], scaled by invn*alpha ===============
__global__ __launch_bounds__(256) void convert_w_kernel(const float* __restrict__ W,
      const float* __restrict__ invn, float alpha, int rows_valid, int K,
      unsigned short* __restrict__ dst) {
  int n = blockIdx.x;
  unsigned short* drow = dst + (size_t)n * K;
  if (n >= rows_valid) {
    for (int c = threadIdx.x * 4; c < K; c += 1024)
      *(ushort4*)(drow + c) = make_ushort4(0, 0, 0, 0);
    return;
  }
  float s = invn[n] * alpha;
  const float* srow = W + (size_t)n * K;
  for (int c = threadIdx.x * 4; c < K; c += 1024) {
    float4 v = *(const float4*)(srow + c);
    *(ushort4*)(drow + c) = f4b(make_float4(v.x*s, v.y*s, v.z*s, v.w*s));
  }
}

// =============== LayerNorm over last dim (1024) -> bf16 ===============
__global__ __launch_bounds__(256) void layernorm_kernel(const float* __restrict__ u,
      const float* __restrict__ w, const float* __restrict__ b,
      unsigned short* __restrict__ out) {
  __shared__ float lds[16];
  size_t r = blockIdx.x;
  const float* row = u + r * DIM_;
  int d = threadIdx.x * 4;
  float4 v = *(const float4*)(row + d);
  float s = v.x + v.y + v.z + v.w;
  float q = v.x*v.x + v.y*v.y + v.z*v.z + v.w*v.w;
#pragma unroll
  for (int off = 32; off > 0; off >>= 1) { s += __shfl_down(s, off); q += __shfl_down(q, off); }
  int wave = threadIdx.x >> 6;
  if ((threadIdx.x & 63) == 0) { lds[wave] = s; lds[8 + wave] = q; }
  __syncthreads();
  float sa = lds[0]+lds[1]+lds[2]+lds[3];
  float sq = lds[8]+lds[9]+lds[10]+lds[11];
  float mu = sa * (1.f / DIM_);
  float var = sq * (1.f / DIM_) - mu * mu;
  float rstd = rsqrtf(var + 1e-5f);
  float4 wv = *(const float4*)(w + d);
  float4 bv = *(const float4*)(b + d);
  float4 o;
  o.x = (v.x - mu) * rstd * wv.x + bv.x;
  o.y = (v.y - mu) * rstd * wv.y + bv.y;
  o.z = (v.z - mu) * rstd * wv.z + bv.z;
  o.w = (v.w - mu) * rstd * wv.w + bv.w;
  *(ushort4*)(out + r * DIM_ + d) = f4b(o);
}

// =============== bf16 MFMA GEMM (m97 structure): C[m,n] = sum_k A[m,k]*Wb[n,k] ===============
template<int K, int EPI>
__global__ __launch_bounds__(256) void gemm_mfma(
    const unsigned short* __restrict__ A, const unsigned short* __restrict__ Wb,
    int Nout, unsigned short* __restrict__ zb, unsigned short* __restrict__ xpre,
    float* __restrict__ dtraw, float* __restrict__ outp)
{
  __shared__ __align__(128) unsigned short lds[8192];  // As: 0..4095, Bs: 4096..8191 (ushort idx)
  const int tid  = threadIdx.x;
  const int lane = tid & 63;
  const int w    = tid >> 6;
  const size_t m0 = (size_t)blockIdx.y * 128;
  const int n0 = blockIdx.x * 128;

  f32x4 acc[4][4];
#pragma unroll
  for (int fi = 0; fi < 4; ++fi)
#pragma unroll
    for (int fj = 0; fj < 4; ++fj)
#pragma unroll
      for (int r = 0; r < 4; ++r) acc[fi][fj][r] = 0.f;

  const size_t Kb = (size_t)K * 2;
  const char* ga0 = (const char*)A  + (m0 + (tid >> 2)) * Kb + (tid & 3) * 16;
  const char* ga1 = ga0 + 64 * Kb;
  const char* gb0 = (const char*)Wb + ((size_t)n0 + (tid >> 2)) * Kb + (tid & 3) * 16;
  const char* gb1 = gb0 + 64 * Kb;
  char* ldsb = (char*)lds;
  const int wseg = w * 1024;

  const int mr0 = (w >> 1) * 64, nc0 = (w & 1) * 64;
  const int afrag_base = (mr0 + (lane & 15)) * 32 + (lane >> 4) * 8;
  const int bfrag_base = 4096 + (nc0 + (lane & 15)) * 32 + (lane >> 4) * 8;

  for (int k0 = 0; k0 < (int)Kb; k0 += 64) {
    __builtin_amdgcn_global_load_lds(
        (const __attribute__((address_space(1))) unsigned int*)(ga0 + k0),
        (__attribute__((address_space(3))) unsigned int*)(ldsb + wseg), 16, 0, 0);
    __builtin_amdgcn_global_load_lds(
        (const __attribute__((address_space(1))) unsigned int*)(ga1 + k0),
        (__attribute__((address_space(3))) unsigned int*)(ldsb + 4096 + wseg), 16, 0, 0);
    __builtin_amdgcn_global_load_lds(
        (const __attribute__((address_space(1))) unsigned int*)(gb0 + k0),
        (__attribute__((address_space(3))) unsigned int*)(ldsb + 8192 + wseg), 16, 0, 0);
    __builtin_amdgcn_global_load_lds(
        (const __attribute__((address_space(1))) unsigned int*)(gb1 + k0),
        (__attribute__((address_space(3))) unsigned int*)(ldsb + 12288 + wseg), 16, 0, 0);
    __syncthreads();

    bf16x8 a[4], b[4];
#pragma unroll
    for (int fi = 0; fi < 4; ++fi) a[fi] = *(const bf16x8*)&lds[afrag_base + fi * 16 * 32];
#pragma unroll
    for (int fj = 0; fj < 4; ++fj) b[fj] = *(const bf16x8*)&lds[bfrag_base + fj * 16 * 32];
#pragma unroll
    for (int fi = 0; fi < 4; ++fi)
#pragma unroll
      for (int fj = 0; fj < 4; ++fj)
        acc[fi][fj] = __builtin_amdgcn_mfma_f32_16x16x32_bf16(a[fi], b[fj], acc[fi][fj], 0, 0, 0);
    __syncthreads();
  }

#pragma unroll
  for (int fj = 0; fj < 4; ++fj) {
    const int n = n0 + nc0 + fj * 16 + (lane & 15);
#pragma unroll
    for (int fi = 0; fi < 4; ++fi) {
#pragma unroll
      for (int r = 0; r < 4; ++r) {
        const size_t m = m0 + mr0 + fi * 16 + (lane >> 4) * 4 + r;
        const float v = acc[fi][fj][r];
        if (EPI == 0) {
          if (n < DINNER_)                   zb[m * DINNER_ + n] = f2b(v);
          else if (n < DINNER_ + CONVD_)     xpre[m * CONVD_ + (n - DINNER_)] = f2b(v);
          else if (n < DPROJ_)               dtraw[m * NH_ + (n - DINNER_ - CONVD_)] = v;
        } else {
          outp[m * (size_t)Nout + n] = v;
        }
      }
    }
  }
}

// =============== depthwise causal conv(4) + SiLU (bf16 in/out) ===============
__global__ __launch_bounds__(256) void conv_silu_kernel(const unsigned short* __restrict__ xpre,
      const float* __restrict__ cw, const float* __restrict__ cb,
      unsigned short* __restrict__ xbc) {
  int c = blockIdx.x * 256 + threadIdx.x;
  if (c >= CONVD_) return;
  int b = blockIdx.z;
  int l0 = blockIdx.y * 64;
  float w0 = cw[c*4+0], w1 = cw[c*4+1], w2 = cw[c*4+2], w3 = cw[c*4+3];
  float bias = cb[c];
  const unsigned short* src = xpre + (size_t)b * SEQL_ * CONVD_ + c;
  float xm3, xm2, xm1;
  if (l0 == 0) { xm3 = 0.f; xm2 = 0.f; xm1 = 0.f; }
  else {
    xm3 = b2f(src[(size_t)(l0-3) * CONVD_]);
    xm2 = b2f(src[(size_t)(l0-2) * CONVD_]);
    xm1 = b2f(src[(size_t)(l0-1) * CONVD_]);
  }
  unsigned short* dst = xbc + ((size_t)b * SEQL_ + l0) * CONVD_ + c;
  for (int t = 0; t < 64; ++t) {
    float x0 = b2f(src[(size_t)(l0 + t) * CONVD_]);
    float v = w0*xm3 + w1*xm2 + w2*xm1 + w3*x0 + bias;
    float sv = v / (1.f + __expf(-v));
    dst[(size_t)t * CONVD_] = f2b(sv);
    xm3 = xm2; xm2 = xm1; xm1 = x0;
  }
}

// =============== dt = softplus(dt_raw + bias); cum = cumsum(dt*A) per chunk ===============
__global__ __launch_bounds__(256) void dtcum_kernel(const float* __restrict__ dtraw,
      const float* __restrict__ dt_bias, const float* __restrict__ A_log,
      float* __restrict__ dtv, float* __restrict__ cum, float* __restrict__ cdec) {
  __shared__ float lds[4];
  int h = blockIdx.x, c = blockIdx.y, b = blockIdx.z;
  int tid = threadIdx.x;
  size_t row = (size_t)b * SEQL_ + c * CHUNKL_ + tid;
  float raw = dtraw[row * NH_ + h] + dt_bias[h];
  float dt = (raw > 20.f) ? raw : log1pf(expf(raw));
  dtv[row * NH_ + h] = dt;
  float v = dt * (-expf(A_log[h]));
  int lane = tid & 63, wave = tid >> 6;
#pragma unroll
  for (int off = 1; off < 64; off <<= 1) {
    float n = __shfl_up(v, off);
    if (lane >= off) v += n;
  }
  if (lane == 63) lds[wave] = v;
  __syncthreads();
  float pre = 0.f;
  for (int w2 = 0; w2 < wave; ++w2) pre += lds[w2];
  v += pre;
  cum[row * NH_ + h] = v;
  if (tid == 255) cdec[((size_t)b * NCHUNK_ + c) * NH_ + h] = __expf(v);
}

// =============== scores[i,j] = C_i . B_j (shared across heads, ngroups=1) ===============
__global__ __launch_bounds__(256) void scores_kernel(const unsigned short* __restrict__ xbc,
                                                     float* __restrict__ scores) {
  __shared__ float Cs[64][64];
  int it = blockIdx.x;  // i-tile of 64
  int c = blockIdx.y, b = blockIdx.z;
  size_t row0 = (size_t)b * SEQL_ + c * CHUNKL_;
  int j = threadIdx.x;
  float Br[64];
  const unsigned short* bp = xbc + (row0 + j) * CONVD_ + DINNER_;
#pragma unroll
  for (int n4 = 0; n4 < 16; ++n4) {
    float4 v = b4f(*(const ushort4*)(bp + n4*4));
    Br[n4*4+0]=v.x; Br[n4*4+1]=v.y; Br[n4*4+2]=v.z; Br[n4*4+3]=v.w;
  }
  {
    int i = threadIdx.x >> 2, q = threadIdx.x & 3;
    const unsigned short* cp = xbc + (row0 + it*64 + i) * CONVD_ + DINNER_ + DSTATE_;
#pragma unroll
    for (int s2 = 0; s2 < 4; ++s2)
      *(float4*)&Cs[i][(q + s2*4)*4] = b4f(*(const ushort4*)(cp + (q + s2*4)*4));
  }
  __syncthreads();
  float* out = scores + ((size_t)b * NCHUNK_ + c) * (CHUNKL_*CHUNKL_) + (size_t)it*64*CHUNKL_ + j;
  for (int i = 0; i < 64; ++i) {
    float s = 0.f;
#pragma unroll
    for (int n = 0; n < 64; ++n) s += Cs[i][n] * Br[n];
    out[(size_t)i * CHUNKL_] = s;
  }
}

// =============== FUSED SSD: y = (att @ x) + (exp(cum)·C @ prevst^T) + D*x  (MFMA) ===============
__global__ __launch_bounds__(256, 2) void ssd_fused_kernel(
    const unsigned short* __restrict__ xbc, const float* __restrict__ scores,
    const float* __restrict__ dtv, const float* __restrict__ cum,
    const float* __restrict__ prevst, const float* __restrict__ Dv,
    unsigned short* __restrict__ y)
{
  __shared__ unsigned short xT[128 * XT_PITCH];  // xT[p][j] = x[j][p]  (69.6 KB)
  __shared__ float cumS[256];
  __shared__ float dtS[256];
  const int h = blockIdx.x, c = blockIdx.y, b = blockIdx.z;
  const size_t row0 = (size_t)b * SEQL_ + c * CHUNKL_;
  const int tid = threadIdx.x;
  const int lane = tid & 63;
  const int w = tid >> 6;
  const int i0 = w * 64;

  cumS[tid] = cum[(row0 + tid) * NH_ + h];
  dtS[tid]  = dtv[(row0 + tid) * NH_ + h];

  {
    const unsigned short* xp = xbc + (row0 + tid) * CONVD_ + (size_t)h * HD_;
#pragma unroll
    for (int q = 0; q < 16; ++q) {
      ushort4 v = *(const ushort4*)(xp + q * 8);
      xT[(q*8+0) * XT_PITCH + tid] = v.x;
      xT[(q*8+1) * XT_PITCH + tid] = v.y;
      xT[(q*8+2) * XT_PITCH + tid] = v.z;
      xT[(q*8+3) * XT_PITCH + tid] = v.w;
      ushort4 v2 = *(const ushort4*)(xp + q * 8 + 4);
      xT[(q*8+4) * XT_PITCH + tid] = v2.x;
      xT[(q*8+5) * XT_PITCH + tid] = v2.y;
      xT[(q*8+6) * XT_PITCH + tid] = v2.z;
      xT[(q*8+7) * XT_PITCH + tid] = v2.w;
    }
  }
  __syncthreads();

  f32x4 acc[4][8];
#pragma unroll
  for (int fi = 0; fi < 4; ++fi)
#pragma unroll
    for (int fj = 0; fj < 8; ++fj)
#pragma unroll
      for (int r = 0; r < 4; ++r) acc[fi][fj][r] = 0.f;

  float cum_i[4];
#pragma unroll
  for (int fi = 0; fi < 4; ++fi) cum_i[fi] = cumS[i0 + fi*16 + (lane & 15)];

  const float* sc_bc = scores + ((size_t)b * NCHUNK_ + c) * (CHUNKL_*CHUNKL_);
  const int nsteps = 2*w + 2;

  for (int jt = 0; jt < nsteps; ++jt) {
    const int j0 = jt*32 + (lane >> 4) * 8;
    float cj[8], dj[8];
    *(float4*)(cj)   = *(const float4*)&cumS[j0];
    *(float4*)(cj+4) = *(const float4*)&cumS[j0 + 4];
    *(float4*)(dj)   = *(const float4*)&dtS[j0];
    *(float4*)(dj+4) = *(const float4*)&dtS[j0 + 4];
    const bool diag = (jt >= 2*w);

    bf16x8 a[4];
#pragma unroll
    for (int fi = 0; fi < 4; ++fi) {
      const int irow = i0 + fi*16 + (lane & 15);
      const float* srow = sc_bc + (size_t)irow * CHUNKL_ + j0;
      float sv[8];
      *(float4*)(sv)   = *(const float4*)srow;
      *(float4*)(sv+4) = *(const float4*)(srow + 4);
      union { bf16x8 v; unsigned short u[8]; } pa;
#pragma unroll
      for (int e = 0; e < 8; ++e) {
        float val = sv[e] * __expf(cum_i[fi] - cj[e]) * dj[e];
        if (diag) val = ((j0 + e) <= irow) ? val : 0.f;
        pa.u[e] = f2b(val);
      }
      a[fi] = pa.v;
    }

    bf16x8 bf[8];
#pragma unroll
    for (int fj = 0; fj < 8; ++fj) {
      const int p = fj*16 + (lane & 15);
      bf[fj] = *(const bf16x8*)&xT[p * XT_PITCH + j0];
    }
#pragma unroll
    for (int fi = 0; fi < 4; ++fi)
#pragma unroll
      for (int fj = 0; fj < 8; ++fj)
        acc[fi][fj] = __builtin_amdgcn_mfma_f32_16x16x32_bf16(a[fi], bf[fj], acc[fi][fj], 0, 0, 0);
  }

  // ---- y_inter: acc += (exp(cum_i)*C) @ prevst^T  (K = 64, 2 steps) ----
  {
    float ec[4];
#pragma unroll
    for (int fi = 0; fi < 4; ++fi) ec[fi] = __expf(cum_i[fi]);
    const float* pbase = prevst + (((size_t)b * NCHUNK_ + c) * NH_ + h) * (HD_ * DSTATE_);
#pragma unroll
    for (int ks = 0; ks < 2; ++ks) {
      const int nk = ks*32 + (lane >> 4) * 8;
      bf16x8 a2[4];
#pragma unroll
      for (int fi = 0; fi < 4; ++fi) {
        const int irow = i0 + fi*16 + (lane & 15);
        const unsigned short* cp = xbc + (row0 + irow) * CONVD_ + DINNER_ + DSTATE_ + nk;
        union { bf16x8 v; unsigned short u[8]; } pin, pout;
        pin.v = *(const bf16x8*)cp;
#pragma unroll
        for (int e = 0; e < 8; ++e) pout.u[e] = f2b(b2f(pin.u[e]) * ec[fi]);
        a2[fi] = pout.v;
      }
      bf16x8 b2[8];
#pragma unroll
      for (int fj = 0; fj < 8; ++fj) {
        const int p = fj*16 + (lane & 15);
        const float* pp = pbase + (size_t)p * DSTATE_ + nk;
        float pv[8];
        *(float4*)(pv)   = *(const float4*)pp;
        *(float4*)(pv+4) = *(const float4*)(pp + 4);
        union { bf16x8 v; unsigned short u[8]; } pb;
#pragma unroll
        for (int e = 0; e < 8; ++e) pb.u[e] = f2b(pv[e]);
        b2[fj] = pb.v;
      }
#pragma unroll
      for (int fi = 0; fi < 4; ++fi)
#pragma unroll
        for (int fj = 0; fj < 8; ++fj)
          acc[fi][fj] = __builtin_amdgcn_mfma_f32_16x16x32_bf16(a2[fi], b2[fj], acc[fi][fj], 0, 0, 0);
    }
  }

  // ---- epilogue: + D*x, store bf16 ----
  const float Dh = Dv[h];
#pragma unroll
  for (int fi = 0; fi < 4; ++fi) {
#pragma unroll
    for (int fj = 0; fj < 8; ++fj) {
      const int p = fj*16 + (lane & 15);
#pragma unroll
      for (int r = 0; r < 4; ++r) {
        const int irow = i0 + fi*16 + (lane >> 4) * 4 + r;
        const float xv = b2f(xT[p * XT_PITCH + irow]);
        y[(row0 + irow) * DINNER_ + (size_t)h * HD_ + p] = f2b(acc[fi][fj][r] + Dh * xv);
      }
    }
  }
}

// =============== MFMA states: states[p][n] = sum_l x[l][p] * (dt_l*exp(cum_end-cum_l)) * B[l][n] ===============
// Grid (h, c, b), 256 thr = 4 waves. M=128 (p, 2 halves of 64), N=64 (n), K=256 (l).
// BT[n][l] staged once with coef folded; xT[p][l] staged per 64-p half (66 KB LDS -> 2 blocks/CU).
__global__ __launch_bounds__(256, 2) void states_mfma_kernel(
    const unsigned short* __restrict__ xbc, const float* __restrict__ dtv,
    const float* __restrict__ cum, float* __restrict__ states)
{
  __shared__ unsigned short BT[64 * ST_PITCH];
  __shared__ unsigned short xT[64 * ST_PITCH];
  const int h = blockIdx.x, c = blockIdx.y, b = blockIdx.z;
  const size_t row0 = (size_t)b * SEQL_ + c * CHUNKL_;
  const int tid = threadIdx.x, lane = tid & 63, w = tid >> 6;

  // thread tid owns l = tid: fold coef_l into BT at stage time (no extra sync needed)
  const float cum_last = cum[(row0 + 255) * NH_ + h];
  const float coef = dtv[(row0 + tid) * NH_ + h] *
                     __expf(cum_last - cum[(row0 + tid) * NH_ + h]);
  {
    const unsigned short* bp = xbc + (row0 + tid) * CONVD_ + DINNER_;
#pragma unroll
    for (int q = 0; q < 16; ++q) {
      ushort4 v = *(const ushort4*)(bp + q * 4);
      BT[(q*4+0) * ST_PITCH + tid] = f2b(b2f(v.x) * coef);
      BT[(q*4+1) * ST_PITCH + tid] = f2b(b2f(v.y) * coef);
      BT[(q*4+2) * ST_PITCH + tid] = f2b(b2f(v.z) * coef);
      BT[(q*4+3) * ST_PITCH + tid] = f2b(b2f(v.w) * coef);
    }
  }

  float* sbase = states + (((size_t)b * NCHUNK_ + c) * NH_ + h) * (HD_ * DSTATE_);

  for (int half = 0; half < 2; ++half) {
    __syncthreads();  // half 0: BT visible before compute; half 1: prev xT reads done
    {
      const unsigned short* xp = xbc + (row0 + tid) * CONVD_ + (size_t)h * HD_ + half * 64;
#pragma unroll
      for (int q = 0; q < 16; ++q) {
        ushort4 v = *(const ushort4*)(xp + q * 4);
        xT[(q*4+0) * ST_PITCH + tid] = v.x;
        xT[(q*4+1) * ST_PITCH + tid] = v.y;
        xT[(q*4+2) * ST_PITCH + tid] = v.z;
        xT[(q*4+3) * ST_PITCH + tid] = v.w;
      }
    }
    __syncthreads();

    f32x4 acc[4];
#pragma unroll
    for (int fj = 0; fj < 4; ++fj)
#pragma unroll
      for (int r = 0; r < 4; ++r) acc[fj][r] = 0.f;

#pragma unroll
    for (int ks = 0; ks < 8; ++ks) {
      const int l0 = ks*32 + (lane >> 4) * 8;
      bf16x8 a = *(const bf16x8*)&xT[(w*16 + (lane & 15)) * ST_PITCH + l0];
#pragma unroll
      for (int fj = 0; fj < 4; ++fj) {
        bf16x8 bb = *(const bf16x8*)&BT[(fj*16 + (lane & 15)) * ST_PITCH + l0];
        acc[fj] = __builtin_amdgcn_mfma_f32_16x16x32_bf16(a, bb, acc[fj], 0, 0, 0);
      }
    }

#pragma unroll
    for (int fj = 0; fj < 4; ++fj) {
      const int n = fj*16 + (lane & 15);
#pragma unroll
      for (int r = 0; r < 4; ++r) {
        const int p = half*64 + w*16 + (lane >> 4) * 4 + r;
        sbase[(size_t)p * DSTATE_ + n] = acc[fj][r];
      }
    }
  }
}

// =============== sequential chunk recurrence: prev[c] = prev[c-1]*cdec[c-1] + states[c-1] ===============
__global__ __launch_bounds__(256) void chunkscan_kernel(const float* __restrict__ states,
      const float* __restrict__ cdec, float* __restrict__ prevst) {
  int h = blockIdx.y, b = blockIdx.z;
  int pn = blockIdx.x * 256 + threadIdx.x;  // 0..8191 = p*64+n
  float carry = 0.f;
  for (int c = 0; c < NCHUNK_; ++c) {
    size_t idx = (((size_t)b * NCHUNK_ + c) * NH_ + h) * (HD_*DSTATE_) + pn;
    prevst[idx] = carry;
    carry = carry * cdec[((size_t)b * NCHUNK_ + c) * NH_ + h] + states[idx];
  }
}

// =============== g = y*silu(z); rmsnorm(g)*rms_w  (bf16 in-place over y) ===============
__global__ __launch_bounds__(256) void gate_rms_kernel(const unsigned short* __restrict__ zb,
      const float* __restrict__ rms_w, unsigned short* __restrict__ y) {
  __shared__ float lds[4];
  size_t r = blockIdx.x;
  const unsigned short* zrow = zb + r * DINNER_;
  unsigned short* yrow = y + r * DINNER_;
  int tid = threadIdx.x;
  float g[8];
  float ss = 0.f;
#pragma unroll
  for (int q = 0; q < 2; ++q) {
    int d = q*1024 + tid*4;
    float4 yv = b4f(*(const ushort4*)(yrow + d));
    float4 zv = b4f(*(const ushort4*)(zrow + d));
    float s0 = zv.x / (1.f + __expf(-zv.x));
    float s1 = zv.y / (1.f + __expf(-zv.y));
    float s2 = zv.z / (1.f + __expf(-zv.z));
    float s3 = zv.w / (1.f + __expf(-zv.w));
    g[q*4+0] = yv.x * s0; g[q*4+1] = yv.y * s1;
    g[q*4+2] = yv.z * s2; g[q*4+3] = yv.w * s3;
    ss += g[q*4+0]*g[q*4+0] + g[q*4+1]*g[q*4+1] + g[q*4+2]*g[q*4+2] + g[q*4+3]*g[q*4+3];
  }
#pragma unroll
  for (int off = 32; off > 0; off >>= 1) ss += __shfl_down(ss, off);
  if ((tid & 63) == 0) lds[tid >> 6] = ss;
  __syncthreads();
  float tot = lds[0] + lds[1] + lds[2] + lds[3];
  float scale = rsqrtf(tot * (1.f / DINNER_) + 1e-5f);
#pragma unroll
  for (int q = 0; q < 2; ++q) {
    int d = q*1024 + tid*4;
    float4 wv = *(const float4*)(rms_w + d);
    *(ushort4*)(yrow + d) = f4b(make_float4(g[q*4+0]*scale*wv.x, g[q*4+1]*scale*wv.y,
                                            g[q*4+2]*scale*wv.z, g[q*4+3]*scale*wv.w));
  }
}

extern "C" void kernel_launch(void* const* d_in, const int* in_sizes, int n_in,
                              void* d_out, int out_size, void* d_ws, size_t ws_size,
                              hipStream_t stream) {
  const float* u       = (const float*)d_in[0];
  const float* in_w    = (const float*)d_in[1];
  const float* conv_w  = (const float*)d_in[2];
  const float* conv_b  = (const float*)d_in[3];
  const float* dt_bias = (const float*)d_in[4];
  const float* A_log   = (const float*)d_in[5];
  const float* Dv      = (const float*)d_in[6];
  const float* xn_w    = (const float*)d_in[7];
  const float* xn_b    = (const float*)d_in[8];
  const float* rms_w   = (const float*)d_in[9];
  const float* out_w   = (const float*)d_in[10];
  float* out = (float*)d_out;

  char* wp = (char*)d_ws;
  auto alloc = [&](size_t bytes) -> void* {
    void* p = (void*)wp; wp += (bytes + 1023) & ~(size_t)1023; return p;
  };
  unsigned short* xpre = (unsigned short*)alloc((size_t)NROWS_ * CONVD_ * 2);  // 35.7MB; y aliases
  unsigned short* y    = xpre;  // y (8192x2048 bf16) reuses xpre after conv consumes it
  unsigned short* zb   = (unsigned short*)alloc((size_t)NROWS_ * DINNER_ * 2); // 33.6MB
  float* dtraw    = (float*)alloc((size_t)NROWS_ * NH_ * 4);
  unsigned short* xbc  = (unsigned short*)alloc((size_t)NROWS_ * CONVD_ * 2);  // 35.7MB
  float* dtv      = (float*)alloc((size_t)NROWS_ * NH_ * 4);
  float* cum      = (float*)alloc((size_t)NROWS_ * NH_ * 4);
  float* cdec     = (float*)alloc((size_t)BATCH_ * NCHUNK_ * NH_ * 4);
  float* invn_in  = (float*)alloc((size_t)DPROJ_ * 4);
  float* invn_out = (float*)alloc((size_t)DIM_ * 4);
  float* scoresB  = (float*)alloc((size_t)BATCH_ * NCHUNK_ * CHUNKL_ * CHUNKL_ * 4); // 8.4MB
  unsigned short* u_ln = (unsigned short*)alloc((size_t)NROWS_ * DIM_ * 2);    // 16.8MB; states aliases
  float* states   = (float*)u_ln;  // states (16.8MB f32) reuses u_ln after in_proj GEMM
  float* prevst   = (float*)alloc((size_t)BATCH_ * NCHUNK_ * NH_ * HD_ * DSTATE_ * 4); // 16.8MB
  unsigned short* wb_in  = (unsigned short*)alloc((size_t)NPAD_ * DIM_ * 2);   // 8.9MB
  unsigned short* wb_out = (unsigned short*)alloc((size_t)DIM_ * DINNER_ * 2); // 4.2MB

  rownorm_kernel<<<DPROJ_, 256, 0, stream>>>(in_w, invn_in, DIM_);
  rownorm_kernel<<<DIM_, 256, 0, stream>>>(out_w, invn_out, DINNER_);
  convert_w_kernel<<<NPAD_, 256, 0, stream>>>(in_w, invn_in, 0.03125f, DPROJ_, DIM_, wb_in);
  convert_w_kernel<<<DIM_, 256, 0, stream>>>(out_w, invn_out, 1.0f, DIM_, DINNER_, wb_out);
  layernorm_kernel<<<NROWS_, 256, 0, stream>>>(u, xn_w, xn_b, u_ln);
  gemm_mfma<DIM_, 0><<<dim3(NPAD_/128, NROWS_/128), 256, 0, stream>>>(
      u_ln, wb_in, 0, zb, xpre, dtraw, nullptr);
  conv_silu_kernel<<<dim3(9, 64, BATCH_), 256, 0, stream>>>(xpre, conv_w, conv_b, xbc);
  dtcum_kernel<<<dim3(NH_, NCHUNK_, BATCH_), 256, 0, stream>>>(dtraw, dt_bias, A_log, dtv, cum, cdec);
  scores_kernel<<<dim3(4, NCHUNK_, BATCH_), 256, 0, stream>>>(xbc, scoresB);
  states_mfma_kernel<<<dim3(NH_, NCHUNK_, BATCH_), 256, 0, stream>>>(xbc, dtv, cum, states);
  chunkscan_kernel<<<dim3(32, NH_, BATCH_), 256, 0, stream>>>(states, cdec, prevst);
  ssd_fused_kernel<<<dim3(NH_, NCHUNK_, BATCH_), 256, 0, stream>>>(
      xbc, scoresB, dtv, cum, prevst, Dv, y);
  gate_rms_kernel<<<NROWS_, 256, 0, stream>>>(zb, rms_w, y);
  gemm_mfma<DINNER_, 1><<<dim3(DIM_/128, NROWS_/128), 256, 0, stream>>>(
      y, wb_out, DIM_, nullptr, nullptr, nullptr, out);
}